// Round 10
// baseline (1380.284 us; speedup 1.0000x reference)
//
#include <hip/hip_runtime.h>
#include <math.h>

#define N_NODES 50000
#define E_RAW   800000
#define E_TOT   850000
#define NEG_SLOPE 0.2f
#define NBC 196   // scan blocks = ceil(50000/256)
#define NCHUNK 12500   // dst-chunks (4 dst each) per col-group

typedef __attribute__((ext_vector_type(8))) short short8;
typedef __attribute__((ext_vector_type(4))) float f32x4;

__device__ __forceinline__ float lrelu(float v) {
    return v >= 0.f ? v : NEG_SLOPE * v;
}
__device__ __forceinline__ unsigned short f2bf(float f) {
    union { float f; unsigned u; } v; v.f = f;
    unsigned r = v.u + 0x7FFF + ((v.u >> 16) & 1);
    return (unsigned short)(r >> 16);
}
__device__ __forceinline__ float bf2f(unsigned short h) {
    union { unsigned u; float f; } v; v.u = ((unsigned)h) << 16;
    return v.f;
}
// h1b/hmid position p holds column C1(p) (16x16 transpose, self-inverse)
__device__ __forceinline__ int C1(int p) { return (p & 15) * 16 + (p >> 4); }
// h2b position p holds column C2(p)
__device__ __forceinline__ int C2(int p) { return (p & 3) * 16 + (p >> 2); }

// ---------------------------------------------------------------------------
// prep (weight frags) + histogram, fused.
// ---------------------------------------------------------------------------
__global__ __launch_bounds__(256) void k_prep_hist(
    const int* __restrict__ dst, int* __restrict__ counts,
    const float* __restrict__ W1, const float* __restrict__ W2,
    unsigned short* __restrict__ Wf1, unsigned short* __restrict__ Wf2)
{
    int idx = blockIdx.x * 256 + threadIdx.x;
    if (idx < 8192) {
        int lane = idx & 63, kb = (idx >> 6) & 7, nb = idx >> 9;
        int c = nb * 16 + (lane & 15);
        int k0 = kb * 32 + ((lane >> 4) & 3) * 8;
        short8 pk;
#pragma unroll
        for (int j = 0; j < 8; ++j)
            pk[j] = (short)f2bf(W1[(k0 + j) * 256 + c]);
        *(short8*)&Wf1[idx * 8] = pk;
    } else if (idx < 10240) {
        int i2 = idx - 8192;
        int lane = i2 & 63, kb = (i2 >> 6) & 7, nb = i2 >> 9;
        int c = nb * 16 + (lane & 15);
        int k0 = kb * 32 + ((lane >> 4) & 3) * 8;
        short8 pk;
#pragma unroll
        for (int j = 0; j < 8; ++j)
            pk[j] = (short)f2bf(W2[C1(k0 + j) * 64 + c]);
        *(short8*)&Wf2[i2 * 8] = pk;
    }
    if (idx < E_TOT) {
        int d = (idx < E_RAW) ? dst[idx] : idx - E_RAW;
        atomicAdd(&counts[d], 1);
    }
}

__global__ __launch_bounds__(256) void k_scan1(
    const int* __restrict__ counts, int* __restrict__ off, int* __restrict__ bsum)
{
    __shared__ int sh[256];
    int t = threadIdx.x, i = blockIdx.x * 256 + t;
    int c = (i < N_NODES) ? counts[i] : 0;
    sh[t] = c; __syncthreads();
    for (int ofs = 1; ofs < 256; ofs <<= 1) {
        int v = (t >= ofs) ? sh[t - ofs] : 0;
        __syncthreads(); sh[t] += v; __syncthreads();
    }
    if (i < N_NODES) off[i] = sh[t] - c;
    if (t == 255) bsum[blockIdx.x] = sh[255];
}

__global__ __launch_bounds__(256) void k_scan2(int* __restrict__ bsum)
{
    __shared__ int sh[256];
    int t = threadIdx.x;
    int c = (t < NBC) ? bsum[t] : 0;
    sh[t] = c; __syncthreads();
    for (int ofs = 1; ofs < 256; ofs <<= 1) {
        int v = (t >= ofs) ? sh[t - ofs] : 0;
        __syncthreads(); sh[t] += v; __syncthreads();
    }
    if (t < NBC) bsum[t] = sh[t] - c;
}

__global__ __launch_bounds__(256) void k_scan3(
    int* __restrict__ off, const int* __restrict__ bsum)
{
    int i = blockIdx.x * 256 + threadIdx.x;
    if (i < N_NODES) off[i] += bsum[blockIdx.x];
    if (i == 0) off[N_NODES] = E_TOT;
}

// ---------------------------------------------------------------------------
// scatter + layer-1 edge weights (SoA by head: aw1h[h*E_TOT + pos]).
// ---------------------------------------------------------------------------
__global__ __launch_bounds__(256) void k_scatter(
    const int* __restrict__ src, const int* __restrict__ dst,
    const int* __restrict__ off, int* __restrict__ cursor,
    const float* __restrict__ as1, const float* __restrict__ ad1,
    unsigned short* __restrict__ esrc, float* __restrict__ aw1h)
{
    int e = blockIdx.x * 256 + threadIdx.x;
    if (e >= E_TOT) return;
    int s, d;
    if (e < E_RAW) { s = src[e]; d = dst[e]; } else { s = e - E_RAW; d = s; }
    int pos = off[d] + atomicAdd(&cursor[d], 1);
    esrc[pos] = (unsigned short)s;
    float4 A = *(const float4*)&as1[s * 4];
    float4 B = *(const float4*)&ad1[d * 4];
    aw1h[0 * E_TOT + pos] = __expf(lrelu(A.x + B.x));
    aw1h[1 * E_TOT + pos] = __expf(lrelu(A.y + B.y));
    aw1h[2 * E_TOT + pos] = __expf(lrelu(A.z + B.z));
    aw1h[3 * E_TOT + pos] = __expf(lrelu(A.w + B.w));
}

// ---------------------------------------------------------------------------
// GEMM1: h1 = x @ W1, MFMA 16x16x32. h1b stored C1-PERMUTED (8B stores).
// Fused att-dot epilogue. (unchanged from round 9)
// ---------------------------------------------------------------------------
__global__ __launch_bounds__(256) void k_gemm1(
    const float* __restrict__ x, const unsigned short* __restrict__ Wf1,
    const float* __restrict__ att_src, const float* __restrict__ att_dst,
    unsigned short* __restrict__ h1b, float* __restrict__ as1, float* __restrict__ ad1)
{
    const int t = threadIdx.x;
    const int lane = t & 63;
    const int w = t >> 6;
    const int rbase = blockIdx.x * 16;
    const int q  = lane & 15;
    const int kg = lane >> 4;
    const int rowA = rbase + q;

    f32x4 acc[4];
#pragma unroll
    for (int nb = 0; nb < 4; ++nb) acc[nb] = (f32x4){0.f, 0.f, 0.f, 0.f};

    short8 b[2][4];
    float4 a0, a1, a0n, a1n;
    {
        const float* ap = &x[rowA * 256 + kg * 8];
        a0 = *(const float4*)ap;
        a1 = *(const float4*)(ap + 4);
#pragma unroll
        for (int nb = 0; nb < 4; ++nb)
            b[0][nb] = *(const short8*)&Wf1[(((w * 4 + nb) * 8 + 0) * 64 + lane) * 8];
    }
#pragma unroll
    for (int kb = 0; kb < 8; ++kb) {
        if (kb < 7) {
            const float* ap = &x[rowA * 256 + (kb + 1) * 32 + kg * 8];
            a0n = *(const float4*)ap;
            a1n = *(const float4*)(ap + 4);
#pragma unroll
            for (int nb = 0; nb < 4; ++nb)
                b[(kb + 1) & 1][nb] =
                    *(const short8*)&Wf1[(((w * 4 + nb) * 8 + kb + 1) * 64 + lane) * 8];
        }
        short8 af;
        af[0] = (short)f2bf(a0.x); af[1] = (short)f2bf(a0.y);
        af[2] = (short)f2bf(a0.z); af[3] = (short)f2bf(a0.w);
        af[4] = (short)f2bf(a1.x); af[5] = (short)f2bf(a1.y);
        af[6] = (short)f2bf(a1.z); af[7] = (short)f2bf(a1.w);
#pragma unroll
        for (int nb = 0; nb < 4; ++nb)
            acc[nb] = __builtin_amdgcn_mfma_f32_16x16x32_bf16(af, b[kb & 1][nb], acc[nb], 0, 0, 0);
        if (kb < 7) { a0 = a0n; a1 = a1n; }
    }

#pragma unroll
    for (int reg = 0; reg < 4; ++reg) {
        int n = rbase + kg * 4 + reg;
        ushort4 pk;
        pk.x = f2bf(acc[0][reg]); pk.y = f2bf(acc[1][reg]);
        pk.z = f2bf(acc[2][reg]); pk.w = f2bf(acc[3][reg]);
        *(ushort4*)&h1b[n * 256 + q * 16 + w * 4] = pk;   // C1-permuted, 8B
    }
    float asv[4], adv[4];
#pragma unroll
    for (int nb = 0; nb < 4; ++nb) {
        int col = (w * 4 + nb) * 16 + q;
        asv[nb] = att_src[col];
        adv[nb] = att_dst[col];
    }
#pragma unroll
    for (int reg = 0; reg < 4; ++reg) {
        float s = acc[0][reg]*asv[0] + acc[1][reg]*asv[1] + acc[2][reg]*asv[2] + acc[3][reg]*asv[3];
        float d = acc[0][reg]*adv[0] + acc[1][reg]*adv[1] + acc[2][reg]*adv[2] + acc[3][reg]*adv[3];
#pragma unroll
        for (int ofs = 1; ofs < 16; ofs <<= 1) {
            s += __shfl_xor(s, ofs);
            d += __shfl_xor(d, ofs);
        }
        if (q == 0) {
            int n = rbase + kg * 4 + reg;
            as1[n * 4 + w] = s;
            ad1[n * 4 + w] = d;
        }
    }
}

// ---------------------------------------------------------------------------
// gather1: XCD-affine column-partitioned gather.
// Work item = (dst-chunk, col-group); 8 queues of 12500 items, queue cg
// served preferentially by blocks physically on XCD cg (s_getreg XCC_ID),
// steal-on-exhaust guarantees every item processed exactly once regardless
// of dispatch. Each XCD then re-reads only its 3.2 MB h1b slice (64 B/row,
// L2-resident). esrc/aw nt-loads, hmid nt-stores keep streams from evicting
// the slice. Wave per dst: lane=(k 0..15, ep 0..3); lane k's dword covers
// C1-positions cg*32+2k,+1 (both head (k&7)>>1); 2x unroll = 8 edges in
// flight; shfl_xor(16,32) reduces acc+denominator over ep groups.
// ---------------------------------------------------------------------------
__global__ __launch_bounds__(256) void k_gather1(
    const unsigned short* __restrict__ esrc, const int* __restrict__ off,
    const float* __restrict__ aw1h,
    const unsigned short* __restrict__ h1b, const float* __restrict__ b1,
    unsigned short* __restrict__ hmid, int* __restrict__ q8)
{
    __shared__ int s_item, s_cg;
    if (threadIdx.x == 0) {
        int xcd;
        asm volatile("s_getreg_b32 %0, hwreg(HW_REG_XCC_ID)" : "=s"(xcd));
        xcd &= 7;
        int cg = xcd;
        int item = atomicAdd(&q8[cg], 1);
        while (item >= NCHUNK) {
            cg = (cg + 1) & 7;
            if (cg == xcd) break;
            item = atomicAdd(&q8[cg], 1);
        }
        s_item = item; s_cg = cg;
    }
    __syncthreads();
    const int item = s_item;
    const int cg   = s_cg;
    if (item >= NCHUNK) return;

    const int t = threadIdx.x;
    const int w = t >> 6;
    const int lane = t & 63;
    const int k  = lane & 15;
    const int ep = lane >> 4;
    const int d = item * 4 + w;
    const int head = (k & 7) >> 1;
    const float* awp = aw1h + head * E_TOT;
    const int e0 = off[d], e1 = off[d + 1];
    const unsigned short* hb = h1b + cg * 32 + k * 2;

    float a0 = 0.f, a1 = 0.f, dn = 0.f;
    int e = e0 + ep;
    for (; e + 4 < e1; e += 8) {
        int sA = __builtin_nontemporal_load(&esrc[e]);
        int sB = __builtin_nontemporal_load(&esrc[e + 4]);
        float wA = __builtin_nontemporal_load(&awp[e]);
        float wB = __builtin_nontemporal_load(&awp[e + 4]);
        unsigned uA = *(const unsigned*)(hb + sA * 256);
        unsigned uB = *(const unsigned*)(hb + sB * 256);
        dn += wA + wB;
        a0 = fmaf(wA, bf2f((unsigned short)uA), fmaf(wB, bf2f((unsigned short)uB), a0));
        a1 = fmaf(wA, bf2f((unsigned short)(uA >> 16)), fmaf(wB, bf2f((unsigned short)(uB >> 16)), a1));
    }
    if (e < e1) {
        int sA = __builtin_nontemporal_load(&esrc[e]);
        float wA = __builtin_nontemporal_load(&awp[e]);
        unsigned uA = *(const unsigned*)(hb + sA * 256);
        dn += wA;
        a0 = fmaf(wA, bf2f((unsigned short)uA), a0);
        a1 = fmaf(wA, bf2f((unsigned short)(uA >> 16)), a1);
    }
    a0 += __shfl_xor(a0, 16); a0 += __shfl_xor(a0, 32);
    a1 += __shfl_xor(a1, 16); a1 += __shfl_xor(a1, 32);
    dn += __shfl_xor(dn, 16); dn += __shfl_xor(dn, 32);
    if (ep == 0) {
        const float inv = 1.f / (dn + 1e-16f);
        int p = cg * 32 + k * 2;
        float v0 = a0 * inv + b1[C1(p)];
        float v1 = a1 * inv + b1[C1(p + 1)];
        v0 = v0 > 0.f ? v0 : expm1f(v0);
        v1 = v1 > 0.f ? v1 : expm1f(v1);
        unsigned pk = (unsigned)f2bf(v0) | ((unsigned)f2bf(v1) << 16);
        __builtin_nontemporal_store(pk, (unsigned*)&hmid[d * 256 + p]);
    }
}

// ---------------------------------------------------------------------------
// GEMM2: h2 = hmid @ W2 (hmid C1-permuted; Wf2 compensates). h2b C2-permuted;
// fused att2 epilogue. (unchanged from round 9)
// ---------------------------------------------------------------------------
__global__ __launch_bounds__(256) void k_gemm2(
    const unsigned short* __restrict__ hmid, const unsigned short* __restrict__ Wf2,
    const float* __restrict__ att_src, const float* __restrict__ att_dst,
    unsigned short* __restrict__ h2b, float* __restrict__ as2, float* __restrict__ ad2)
{
    const int t = threadIdx.x;
    const int lane = t & 63;
    const int w = t >> 6;
    const int rbase = blockIdx.x * 64 + w * 16;
    const int q  = lane & 15;
    const int kg = lane >> 4;
    const int rowA = rbase + q;
    const int rA = rowA < N_NODES ? rowA : N_NODES - 1;

    f32x4 acc[4];
#pragma unroll
    for (int nb = 0; nb < 4; ++nb) acc[nb] = (f32x4){0.f, 0.f, 0.f, 0.f};

    short8 b[2][4];
    short8 af, afn;
    af = *(const short8*)&hmid[rA * 256 + kg * 8];
#pragma unroll
    for (int nb = 0; nb < 4; ++nb)
        b[0][nb] = *(const short8*)&Wf2[((nb * 8 + 0) * 64 + lane) * 8];
#pragma unroll
    for (int kb = 0; kb < 8; ++kb) {
        if (kb < 7) {
            afn = *(const short8*)&hmid[rA * 256 + (kb + 1) * 32 + kg * 8];
#pragma unroll
            for (int nb = 0; nb < 4; ++nb)
                b[(kb + 1) & 1][nb] = *(const short8*)&Wf2[((nb * 8 + kb + 1) * 64 + lane) * 8];
        }
#pragma unroll
        for (int nb = 0; nb < 4; ++nb)
            acc[nb] = __builtin_amdgcn_mfma_f32_16x16x32_bf16(af, b[kb & 1][nb], acc[nb], 0, 0, 0);
        if (kb < 7) af = afn;
    }

    float asv[4], adv[4];
#pragma unroll
    for (int nb = 0; nb < 4; ++nb) {
        int col = nb * 16 + q;
        asv[nb] = att_src[col];
        adv[nb] = att_dst[col];
    }
#pragma unroll
    for (int reg = 0; reg < 4; ++reg) {
        int n = rbase + kg * 4 + reg;
        bool ok = n < N_NODES;
        if (ok) {
            ushort4 pk;
            pk.x = f2bf(acc[0][reg]); pk.y = f2bf(acc[1][reg]);
            pk.z = f2bf(acc[2][reg]); pk.w = f2bf(acc[3][reg]);
            *(ushort4*)&h2b[n * 64 + q * 4] = pk;
        }
        float s = acc[0][reg]*asv[0] + acc[1][reg]*asv[1] + acc[2][reg]*asv[2] + acc[3][reg]*asv[3];
        float d = acc[0][reg]*adv[0] + acc[1][reg]*adv[1] + acc[2][reg]*adv[2] + acc[3][reg]*adv[3];
#pragma unroll
        for (int ofs = 1; ofs < 16; ofs <<= 1) {
            s += __shfl_xor(s, ofs);
            d += __shfl_xor(d, ofs);
        }
        if (ok && q == 0) { as2[n] = s; ad2[n] = d; }
    }
}

// ---------------------------------------------------------------------------
// gather2: 4 dst per wave, 4x unroll, inline exp. (unchanged from round 9)
// ---------------------------------------------------------------------------
__global__ __launch_bounds__(256) void k_gather2(
    const unsigned short* __restrict__ esrc, const int* __restrict__ off,
    const float* __restrict__ as2, const float* __restrict__ ad2,
    const unsigned short* __restrict__ h2b, const float* __restrict__ b2,
    float* __restrict__ out)
{
    const int t = threadIdx.x;
    const int w = t >> 6;
    const int lane = t & 63;
    const int g  = lane >> 4;
    const int j2 = lane & 15;
    const int d = blockIdx.x * 16 + w * 4 + g;      // 3125*16 = 50000 exact
    const float adv = ad2[d];
    const int e0 = off[d], e1 = off[d + 1];
    const unsigned short* hb = h2b + j2 * 4;

    float acc[4] = {0.f, 0.f, 0.f, 0.f};
    float dn = 0.f;
    int e = e0;
    for (; e + 3 < e1; e += 4) {
        int s0 = esrc[e], s1 = esrc[e + 1], s2 = esrc[e + 2], s3 = esrc[e + 3];
        float w0 = __expf(lrelu(as2[s0] + adv));
        float w1 = __expf(lrelu(as2[s1] + adv));
        float w2 = __expf(lrelu(as2[s2] + adv));
        float w3 = __expf(lrelu(as2[s3] + adv));
        ushort4 u0 = *(const ushort4*)(hb + s0 * 64);
        ushort4 u1 = *(const ushort4*)(hb + s1 * 64);
        ushort4 u2 = *(const ushort4*)(hb + s2 * 64);
        ushort4 u3 = *(const ushort4*)(hb + s3 * 64);
        dn += (w0 + w1) + (w2 + w3);
        acc[0] = fmaf(w0, bf2f(u0.x), fmaf(w1, bf2f(u1.x), fmaf(w2, bf2f(u2.x), fmaf(w3, bf2f(u3.x), acc[0]))));
        acc[1] = fmaf(w0, bf2f(u0.y), fmaf(w1, bf2f(u1.y), fmaf(w2, bf2f(u2.y), fmaf(w3, bf2f(u3.y), acc[1]))));
        acc[2] = fmaf(w0, bf2f(u0.z), fmaf(w1, bf2f(u1.z), fmaf(w2, bf2f(u2.z), fmaf(w3, bf2f(u3.z), acc[2]))));
        acc[3] = fmaf(w0, bf2f(u0.w), fmaf(w1, bf2f(u1.w), fmaf(w2, bf2f(u2.w), fmaf(w3, bf2f(u3.w), acc[3]))));
    }
    for (; e < e1; ++e) {
        int s0 = esrc[e];
        float w0 = __expf(lrelu(as2[s0] + adv));
        ushort4 u0 = *(const ushort4*)(hb + s0 * 64);
        dn += w0;
        acc[0] = fmaf(w0, bf2f(u0.x), acc[0]);
        acc[1] = fmaf(w0, bf2f(u0.y), acc[1]);
        acc[2] = fmaf(w0, bf2f(u0.z), acc[2]);
        acc[3] = fmaf(w0, bf2f(u0.w), acc[3]);
    }
    const float inv = 1.f / (dn + 1e-16f);
#pragma unroll
    for (int i = 0; i < 4; ++i) {
        int col = i * 16 + j2;                      // C2(j2*4+i)
        out[d * 64 + col] = acc[i] * inv + b2[col];
    }
}

// ---------------------------------------------------------------------------
// Workspace layout (bytes), total ~69.3 MB:
//   counts @ 0            200,000  [zeroed]
//   cursor @ 200,000      200,000  [zeroed]
//   q8     @ 400,000      32       [zeroed]
//   off    @ 400,032      200,004
//   bsum   @ 600,064      800
//   as1    @ 600,896      800,000
//   ad1    @ 1,400,896    800,000
//   as2    @ 2,200,896    200,000
//   ad2    @ 2,400,896    200,000
//   esrc   @ 2,600,896    1,700,000  uint16
//   Wf1    @ 4,300,896    131,072
//   Wf2    @ 4,431,968    32,768
//   aw1h   @ 4,464,736    13,600,000 f32 SoA [4][E_TOT]
//   h1b    @ 18,064,736   25,600,000 bf16 C1-perm (h2b reuses after gather1)
//   h2b    @ 18,064,736   6,400,000  bf16 C2-perm
//   hmid   @ 43,664,736   25,600,000 bf16 C1-perm
// ---------------------------------------------------------------------------
extern "C" void kernel_launch(void* const* d_in, const int* in_sizes, int n_in,
                              void* d_out, int out_size, void* d_ws, size_t ws_size,
                              hipStream_t stream)
{
    const float* x        = (const float*)d_in[0];
    const int*   ei       = (const int*)d_in[1];
    const float* W1       = (const float*)d_in[2];
    const float* att_src1 = (const float*)d_in[3];
    const float* att_dst1 = (const float*)d_in[4];
    const float* b1       = (const float*)d_in[5];
    const float* W2       = (const float*)d_in[6];
    const float* att_src2 = (const float*)d_in[7];
    const float* att_dst2 = (const float*)d_in[8];
    const float* b2       = (const float*)d_in[9];
    const int* src = ei;
    const int* dst = ei + E_RAW;
    float* out = (float*)d_out;

    char* ws = (char*)d_ws;
    int*            counts = (int*)(ws + 0);
    int*            cursor = (int*)(ws + 200000);
    int*            q8     = (int*)(ws + 400000);
    int*            off    = (int*)(ws + 400032);
    int*            bsum   = (int*)(ws + 600064);
    float*          as1    = (float*)(ws + 600896);
    float*          ad1    = (float*)(ws + 1400896);
    float*          as2    = (float*)(ws + 2200896);
    float*          ad2    = (float*)(ws + 2400896);
    unsigned short* esrc   = (unsigned short*)(ws + 2600896);
    unsigned short* Wf1    = (unsigned short*)(ws + 4300896);
    unsigned short* Wf2    = (unsigned short*)(ws + 4431968);
    float*          aw1h   = (float*)(ws + 4464736);
    unsigned short* h1b    = (unsigned short*)(ws + 18064736);
    unsigned short* h2b    = (unsigned short*)(ws + 18064736);  // reuses h1b
    unsigned short* hmid   = (unsigned short*)(ws + 43664736);

    hipMemsetAsync(ws, 0, 400032, stream);      // counts + cursor + q8

    const int EB = (E_TOT + 255) / 256;
    k_prep_hist<<<EB, 256, 0, stream>>>(dst, counts, W1, W2, Wf1, Wf2);
    k_scan1  <<<NBC, 256, 0, stream>>>(counts, off, bsum);
    k_scan2  <<<1, 256, 0, stream>>>(bsum);
    k_scan3  <<<NBC, 256, 0, stream>>>(off, bsum);
    k_gemm1  <<<3125, 256, 0, stream>>>(x, Wf1, att_src1, att_dst1, h1b, as1, ad1);
    k_scatter<<<EB, 256, 0, stream>>>(src, dst, off, cursor, as1, ad1, esrc, aw1h);
    k_gather1<<<8 * NCHUNK, 256, 0, stream>>>(esrc, off, aw1h, h1b, b1, hmid, q8);
    k_gemm2  <<<782, 256, 0, stream>>>(hmid, Wf2, att_src2, att_dst2, h2b, as2, ad2);
    k_gather2<<<3125, 256, 0, stream>>>(esrc, off, as2, ad2, h2b, b2, out);
}

// Round 11
// 258.489 us; speedup vs baseline: 5.3398x; 5.3398x over previous
//
#include <hip/hip_runtime.h>
#include <math.h>

#define N_NODES 50000
#define E_RAW   800000
#define E_TOT   850000
#define NEG_SLOPE 0.2f
#define NBC 196   // scan blocks = ceil(50000/256)

typedef __attribute__((ext_vector_type(8))) short short8;
typedef __attribute__((ext_vector_type(4))) float f32x4;

__device__ __forceinline__ float lrelu(float v) {
    return v >= 0.f ? v : NEG_SLOPE * v;
}
__device__ __forceinline__ unsigned short f2bf(float f) {
    union { float f; unsigned u; } v; v.f = f;
    unsigned r = v.u + 0x7FFF + ((v.u >> 16) & 1);
    return (unsigned short)(r >> 16);
}
__device__ __forceinline__ float bf2f(unsigned short h) {
    union { unsigned u; float f; } v; v.u = ((unsigned)h) << 16;
    return v.f;
}
// h1b/hmid position p holds column C1(p) (16x16 transpose, self-inverse)
__device__ __forceinline__ int C1(int p) { return (p & 15) * 16 + (p >> 4); }
// h2b position p holds column C2(p)
__device__ __forceinline__ int C2(int p) { return (p & 3) * 16 + (p >> 2); }

// ---------------------------------------------------------------------------
// prep (weight frags) + histogram, fused.
// ---------------------------------------------------------------------------
__global__ __launch_bounds__(256) void k_prep_hist(
    const int* __restrict__ dst, int* __restrict__ counts,
    const float* __restrict__ W1, const float* __restrict__ W2,
    unsigned short* __restrict__ Wf1, unsigned short* __restrict__ Wf2)
{
    int idx = blockIdx.x * 256 + threadIdx.x;
    if (idx < 8192) {
        int lane = idx & 63, kb = (idx >> 6) & 7, nb = idx >> 9;
        int c = nb * 16 + (lane & 15);
        int k0 = kb * 32 + ((lane >> 4) & 3) * 8;
        short8 pk;
#pragma unroll
        for (int j = 0; j < 8; ++j)
            pk[j] = (short)f2bf(W1[(k0 + j) * 256 + c]);
        *(short8*)&Wf1[idx * 8] = pk;
    } else if (idx < 10240) {
        int i2 = idx - 8192;
        int lane = i2 & 63, kb = (i2 >> 6) & 7, nb = i2 >> 9;
        int c = nb * 16 + (lane & 15);
        int k0 = kb * 32 + ((lane >> 4) & 3) * 8;
        short8 pk;
#pragma unroll
        for (int j = 0; j < 8; ++j)
            pk[j] = (short)f2bf(W2[C1(k0 + j) * 64 + c]);
        *(short8*)&Wf2[i2 * 8] = pk;
    }
    if (idx < E_TOT) {
        int d = (idx < E_RAW) ? dst[idx] : idx - E_RAW;
        atomicAdd(&counts[d], 1);
    }
}

__global__ __launch_bounds__(256) void k_scan1(
    const int* __restrict__ counts, int* __restrict__ off, int* __restrict__ bsum)
{
    __shared__ int sh[256];
    int t = threadIdx.x, i = blockIdx.x * 256 + t;
    int c = (i < N_NODES) ? counts[i] : 0;
    sh[t] = c; __syncthreads();
    for (int ofs = 1; ofs < 256; ofs <<= 1) {
        int v = (t >= ofs) ? sh[t - ofs] : 0;
        __syncthreads(); sh[t] += v; __syncthreads();
    }
    if (i < N_NODES) off[i] = sh[t] - c;
    if (t == 255) bsum[blockIdx.x] = sh[255];
}

__global__ __launch_bounds__(256) void k_scan2(int* __restrict__ bsum)
{
    __shared__ int sh[256];
    int t = threadIdx.x;
    int c = (t < NBC) ? bsum[t] : 0;
    sh[t] = c; __syncthreads();
    for (int ofs = 1; ofs < 256; ofs <<= 1) {
        int v = (t >= ofs) ? sh[t - ofs] : 0;
        __syncthreads(); sh[t] += v; __syncthreads();
    }
    if (t < NBC) bsum[t] = sh[t] - c;
}

__global__ __launch_bounds__(256) void k_scan3(
    int* __restrict__ off, const int* __restrict__ bsum)
{
    int i = blockIdx.x * 256 + threadIdx.x;
    if (i < N_NODES) off[i] += bsum[blockIdx.x];
    if (i == 0) off[N_NODES] = E_TOT;
}

// ---------------------------------------------------------------------------
// scatter + layer-1 edge weights (AoS float4 at CSR position).
// ---------------------------------------------------------------------------
__global__ __launch_bounds__(256) void k_scatter(
    const int* __restrict__ src, const int* __restrict__ dst,
    const int* __restrict__ off, int* __restrict__ cursor,
    const float* __restrict__ as1, const float* __restrict__ ad1,
    unsigned short* __restrict__ esrc, float* __restrict__ aw1)
{
    int e = blockIdx.x * 256 + threadIdx.x;
    if (e >= E_TOT) return;
    int s, d;
    if (e < E_RAW) { s = src[e]; d = dst[e]; } else { s = e - E_RAW; d = s; }
    int pos = off[d] + atomicAdd(&cursor[d], 1);
    esrc[pos] = (unsigned short)s;
    float4 A = *(const float4*)&as1[s * 4];
    float4 B = *(const float4*)&ad1[d * 4];
    float4 w;
    w.x = __expf(lrelu(A.x + B.x));
    w.y = __expf(lrelu(A.y + B.y));
    w.z = __expf(lrelu(A.z + B.z));
    w.w = __expf(lrelu(A.w + B.w));
    *(float4*)&aw1[pos * 4] = w;
}

// ---------------------------------------------------------------------------
// GEMM1: h1 = x @ W1, MFMA 16x16x32. h1b stored C1-PERMUTED (8B stores).
// Fused att-dot epilogue. (r9, unchanged)
// ---------------------------------------------------------------------------
__global__ __launch_bounds__(256) void k_gemm1(
    const float* __restrict__ x, const unsigned short* __restrict__ Wf1,
    const float* __restrict__ att_src, const float* __restrict__ att_dst,
    unsigned short* __restrict__ h1b, float* __restrict__ as1, float* __restrict__ ad1)
{
    const int t = threadIdx.x;
    const int lane = t & 63;
    const int w = t >> 6;
    const int rbase = blockIdx.x * 16;
    const int q  = lane & 15;
    const int kg = lane >> 4;
    const int rowA = rbase + q;

    f32x4 acc[4];
#pragma unroll
    for (int nb = 0; nb < 4; ++nb) acc[nb] = (f32x4){0.f, 0.f, 0.f, 0.f};

    short8 b[2][4];
    float4 a0, a1, a0n, a1n;
    {
        const float* ap = &x[rowA * 256 + kg * 8];
        a0 = *(const float4*)ap;
        a1 = *(const float4*)(ap + 4);
#pragma unroll
        for (int nb = 0; nb < 4; ++nb)
            b[0][nb] = *(const short8*)&Wf1[(((w * 4 + nb) * 8 + 0) * 64 + lane) * 8];
    }
#pragma unroll
    for (int kb = 0; kb < 8; ++kb) {
        if (kb < 7) {
            const float* ap = &x[rowA * 256 + (kb + 1) * 32 + kg * 8];
            a0n = *(const float4*)ap;
            a1n = *(const float4*)(ap + 4);
#pragma unroll
            for (int nb = 0; nb < 4; ++nb)
                b[(kb + 1) & 1][nb] =
                    *(const short8*)&Wf1[(((w * 4 + nb) * 8 + kb + 1) * 64 + lane) * 8];
        }
        short8 af;
        af[0] = (short)f2bf(a0.x); af[1] = (short)f2bf(a0.y);
        af[2] = (short)f2bf(a0.z); af[3] = (short)f2bf(a0.w);
        af[4] = (short)f2bf(a1.x); af[5] = (short)f2bf(a1.y);
        af[6] = (short)f2bf(a1.z); af[7] = (short)f2bf(a1.w);
#pragma unroll
        for (int nb = 0; nb < 4; ++nb)
            acc[nb] = __builtin_amdgcn_mfma_f32_16x16x32_bf16(af, b[kb & 1][nb], acc[nb], 0, 0, 0);
        if (kb < 7) { a0 = a0n; a1 = a1n; }
    }

#pragma unroll
    for (int reg = 0; reg < 4; ++reg) {
        int n = rbase + kg * 4 + reg;
        ushort4 pk;
        pk.x = f2bf(acc[0][reg]); pk.y = f2bf(acc[1][reg]);
        pk.z = f2bf(acc[2][reg]); pk.w = f2bf(acc[3][reg]);
        *(ushort4*)&h1b[n * 256 + q * 16 + w * 4] = pk;   // C1-permuted, 8B
    }
    float asv[4], adv[4];
#pragma unroll
    for (int nb = 0; nb < 4; ++nb) {
        int col = (w * 4 + nb) * 16 + q;
        asv[nb] = att_src[col];
        adv[nb] = att_dst[col];
    }
#pragma unroll
    for (int reg = 0; reg < 4; ++reg) {
        float s = acc[0][reg]*asv[0] + acc[1][reg]*asv[1] + acc[2][reg]*asv[2] + acc[3][reg]*asv[3];
        float d = acc[0][reg]*adv[0] + acc[1][reg]*adv[1] + acc[2][reg]*adv[2] + acc[3][reg]*adv[3];
#pragma unroll
        for (int ofs = 1; ofs < 16; ofs <<= 1) {
            s += __shfl_xor(s, ofs);
            d += __shfl_xor(d, ofs);
        }
        if (q == 0) {
            int n = rbase + kg * 4 + reg;
            as1[n * 4 + w] = s;
            ad1[n * 4 + w] = d;
        }
    }
}

// ---------------------------------------------------------------------------
// gather1: r9-proven structure — wave per dst, lane owns C1-positions
// lane*4..+3 (head = lane&3), precomputed aw1, now 8x edge unroll for MLP.
// ---------------------------------------------------------------------------
__global__ __launch_bounds__(256) void k_gather1(
    const unsigned short* __restrict__ esrc, const int* __restrict__ off,
    const float* __restrict__ aw1,
    const unsigned short* __restrict__ h1b, const float* __restrict__ b1,
    unsigned short* __restrict__ hmid)
{
    int d    = (blockIdx.x * 256 + threadIdx.x) >> 6;   // 12500*4 = 50000 exact
    int lane = threadIdx.x & 63;
    const int head = lane & 3;
    const int e0 = off[d], e1 = off[d + 1];
    float4 acc = make_float4(0.f, 0.f, 0.f, 0.f);
    float dn = 0.f;
    int e = e0;
    for (; e + 7 < e1; e += 8) {
        int s0 = esrc[e],     s1 = esrc[e + 1], s2 = esrc[e + 2], s3 = esrc[e + 3];
        int s4 = esrc[e + 4], s5 = esrc[e + 5], s6 = esrc[e + 6], s7 = esrc[e + 7];
        float w0 = aw1[(e + 0) * 4 + head], w1 = aw1[(e + 1) * 4 + head];
        float w2 = aw1[(e + 2) * 4 + head], w3 = aw1[(e + 3) * 4 + head];
        float w4 = aw1[(e + 4) * 4 + head], w5 = aw1[(e + 5) * 4 + head];
        float w6 = aw1[(e + 6) * 4 + head], w7 = aw1[(e + 7) * 4 + head];
        ushort4 u0 = *(const ushort4*)&h1b[s0 * 256 + lane * 4];
        ushort4 u1 = *(const ushort4*)&h1b[s1 * 256 + lane * 4];
        ushort4 u2 = *(const ushort4*)&h1b[s2 * 256 + lane * 4];
        ushort4 u3 = *(const ushort4*)&h1b[s3 * 256 + lane * 4];
        ushort4 u4 = *(const ushort4*)&h1b[s4 * 256 + lane * 4];
        ushort4 u5 = *(const ushort4*)&h1b[s5 * 256 + lane * 4];
        ushort4 u6 = *(const ushort4*)&h1b[s6 * 256 + lane * 4];
        ushort4 u7 = *(const ushort4*)&h1b[s7 * 256 + lane * 4];
        dn += ((w0 + w1) + (w2 + w3)) + ((w4 + w5) + (w6 + w7));
        acc.x = fmaf(w0, bf2f(u0.x), fmaf(w1, bf2f(u1.x), fmaf(w2, bf2f(u2.x), fmaf(w3, bf2f(u3.x), acc.x))));
        acc.y = fmaf(w0, bf2f(u0.y), fmaf(w1, bf2f(u1.y), fmaf(w2, bf2f(u2.y), fmaf(w3, bf2f(u3.y), acc.y))));
        acc.z = fmaf(w0, bf2f(u0.z), fmaf(w1, bf2f(u1.z), fmaf(w2, bf2f(u2.z), fmaf(w3, bf2f(u3.z), acc.z))));
        acc.w = fmaf(w0, bf2f(u0.w), fmaf(w1, bf2f(u1.w), fmaf(w2, bf2f(u2.w), fmaf(w3, bf2f(u3.w), acc.w))));
        acc.x = fmaf(w4, bf2f(u4.x), fmaf(w5, bf2f(u5.x), fmaf(w6, bf2f(u6.x), fmaf(w7, bf2f(u7.x), acc.x))));
        acc.y = fmaf(w4, bf2f(u4.y), fmaf(w5, bf2f(u5.y), fmaf(w6, bf2f(u6.y), fmaf(w7, bf2f(u7.y), acc.y))));
        acc.z = fmaf(w4, bf2f(u4.z), fmaf(w5, bf2f(u5.z), fmaf(w6, bf2f(u6.z), fmaf(w7, bf2f(u7.z), acc.z))));
        acc.w = fmaf(w4, bf2f(u4.w), fmaf(w5, bf2f(u5.w), fmaf(w6, bf2f(u6.w), fmaf(w7, bf2f(u7.w), acc.w))));
    }
    for (; e + 3 < e1; e += 4) {
        int s0 = esrc[e], s1 = esrc[e + 1], s2 = esrc[e + 2], s3 = esrc[e + 3];
        float w0 = aw1[(e + 0) * 4 + head], w1 = aw1[(e + 1) * 4 + head];
        float w2 = aw1[(e + 2) * 4 + head], w3 = aw1[(e + 3) * 4 + head];
        ushort4 u0 = *(const ushort4*)&h1b[s0 * 256 + lane * 4];
        ushort4 u1 = *(const ushort4*)&h1b[s1 * 256 + lane * 4];
        ushort4 u2 = *(const ushort4*)&h1b[s2 * 256 + lane * 4];
        ushort4 u3 = *(const ushort4*)&h1b[s3 * 256 + lane * 4];
        dn += (w0 + w1) + (w2 + w3);
        acc.x = fmaf(w0, bf2f(u0.x), fmaf(w1, bf2f(u1.x), fmaf(w2, bf2f(u2.x), fmaf(w3, bf2f(u3.x), acc.x))));
        acc.y = fmaf(w0, bf2f(u0.y), fmaf(w1, bf2f(u1.y), fmaf(w2, bf2f(u2.y), fmaf(w3, bf2f(u3.y), acc.y))));
        acc.z = fmaf(w0, bf2f(u0.z), fmaf(w1, bf2f(u1.z), fmaf(w2, bf2f(u2.z), fmaf(w3, bf2f(u3.z), acc.z))));
        acc.w = fmaf(w0, bf2f(u0.w), fmaf(w1, bf2f(u1.w), fmaf(w2, bf2f(u2.w), fmaf(w3, bf2f(u3.w), acc.w))));
    }
    for (; e < e1; ++e) {
        int s0 = esrc[e];
        float w0 = aw1[e * 4 + head];
        ushort4 u0 = *(const ushort4*)&h1b[s0 * 256 + lane * 4];
        dn += w0;
        acc.x = fmaf(w0, bf2f(u0.x), acc.x);
        acc.y = fmaf(w0, bf2f(u0.y), acc.y);
        acc.z = fmaf(w0, bf2f(u0.z), acc.z);
        acc.w = fmaf(w0, bf2f(u0.w), acc.w);
    }
    const float inv = 1.f / (dn + 1e-16f);
    float o[4] = {acc.x, acc.y, acc.z, acc.w};
    ushort4 pk;
    unsigned short* pko = (unsigned short*)&pk;
#pragma unroll
    for (int i = 0; i < 4; ++i) {
        float v = o[i] * inv + b1[C1(lane * 4 + i)];
        v = v > 0.f ? v : expm1f(v);
        pko[i] = f2bf(v);
    }
    *(ushort4*)&hmid[d * 256 + lane * 4] = pk;          // C1-permuted, 8B
}

// ---------------------------------------------------------------------------
// GEMM2: h2 = hmid @ W2 (hmid C1-permuted; Wf2 compensates). h2b C2-permuted;
// fused att2 epilogue. (r9, unchanged)
// ---------------------------------------------------------------------------
__global__ __launch_bounds__(256) void k_gemm2(
    const unsigned short* __restrict__ hmid, const unsigned short* __restrict__ Wf2,
    const float* __restrict__ att_src, const float* __restrict__ att_dst,
    unsigned short* __restrict__ h2b, float* __restrict__ as2, float* __restrict__ ad2)
{
    const int t = threadIdx.x;
    const int lane = t & 63;
    const int w = t >> 6;
    const int rbase = blockIdx.x * 64 + w * 16;
    const int q  = lane & 15;
    const int kg = lane >> 4;
    const int rowA = rbase + q;
    const int rA = rowA < N_NODES ? rowA : N_NODES - 1;

    f32x4 acc[4];
#pragma unroll
    for (int nb = 0; nb < 4; ++nb) acc[nb] = (f32x4){0.f, 0.f, 0.f, 0.f};

    short8 b[2][4];
    short8 af, afn;
    af = *(const short8*)&hmid[rA * 256 + kg * 8];
#pragma unroll
    for (int nb = 0; nb < 4; ++nb)
        b[0][nb] = *(const short8*)&Wf2[((nb * 8 + 0) * 64 + lane) * 8];
#pragma unroll
    for (int kb = 0; kb < 8; ++kb) {
        if (kb < 7) {
            afn = *(const short8*)&hmid[rA * 256 + (kb + 1) * 32 + kg * 8];
#pragma unroll
            for (int nb = 0; nb < 4; ++nb)
                b[(kb + 1) & 1][nb] = *(const short8*)&Wf2[((nb * 8 + kb + 1) * 64 + lane) * 8];
        }
#pragma unroll
        for (int nb = 0; nb < 4; ++nb)
            acc[nb] = __builtin_amdgcn_mfma_f32_16x16x32_bf16(af, b[kb & 1][nb], acc[nb], 0, 0, 0);
        if (kb < 7) af = afn;
    }

    float asv[4], adv[4];
#pragma unroll
    for (int nb = 0; nb < 4; ++nb) {
        int col = nb * 16 + q;
        asv[nb] = att_src[col];
        adv[nb] = att_dst[col];
    }
#pragma unroll
    for (int reg = 0; reg < 4; ++reg) {
        int n = rbase + kg * 4 + reg;
        bool ok = n < N_NODES;
        if (ok) {
            ushort4 pk;
            pk.x = f2bf(acc[0][reg]); pk.y = f2bf(acc[1][reg]);
            pk.z = f2bf(acc[2][reg]); pk.w = f2bf(acc[3][reg]);
            *(ushort4*)&h2b[n * 64 + q * 4] = pk;
        }
        float s = acc[0][reg]*asv[0] + acc[1][reg]*asv[1] + acc[2][reg]*asv[2] + acc[3][reg]*asv[3];
        float d = acc[0][reg]*adv[0] + acc[1][reg]*adv[1] + acc[2][reg]*adv[2] + acc[3][reg]*adv[3];
#pragma unroll
        for (int ofs = 1; ofs < 16; ofs <<= 1) {
            s += __shfl_xor(s, ofs);
            d += __shfl_xor(d, ofs);
        }
        if (ok && q == 0) { as2[n] = s; ad2[n] = d; }
    }
}

// ---------------------------------------------------------------------------
// alpha2: unnormalized layer-2 edge weights, f32 in CSR order (write-only;
// gather2 accumulates the denominator itself). Wave per dst, lane = edge.
// ---------------------------------------------------------------------------
__global__ __launch_bounds__(256) void k_alpha2(
    const unsigned short* __restrict__ esrc, const int* __restrict__ off,
    const float* __restrict__ as2, const float* __restrict__ ad2,
    float* __restrict__ aw2)
{
    int d    = (blockIdx.x * 256 + threadIdx.x) >> 6;   // 12500*4 = 50000 exact
    int lane = threadIdx.x & 63;
    const float adv = ad2[d];
    const int e0 = off[d], e1 = off[d + 1];
    for (int e = e0 + lane; e < e1; e += 64) {
        int s = esrc[e];
        aw2[e] = __expf(lrelu(as2[s] + adv));
    }
}

// ---------------------------------------------------------------------------
// gather2: 4 dst per wave (16-lane group owns ushort4 = 128B row), 4x unroll,
// precomputed aw2 -> pure loads+fma. Writes d_out (un-permuting C2).
// ---------------------------------------------------------------------------
__global__ __launch_bounds__(256) void k_gather2(
    const unsigned short* __restrict__ esrc, const int* __restrict__ off,
    const float* __restrict__ aw2,
    const unsigned short* __restrict__ h2b, const float* __restrict__ b2,
    float* __restrict__ out)
{
    const int t = threadIdx.x;
    const int w = t >> 6;
    const int lane = t & 63;
    const int g  = lane >> 4;
    const int j2 = lane & 15;
    const int d = blockIdx.x * 16 + w * 4 + g;      // 3125*16 = 50000 exact
    const int e0 = off[d], e1 = off[d + 1];
    const unsigned short* hb = h2b + j2 * 4;

    float acc[4] = {0.f, 0.f, 0.f, 0.f};
    float dn = 0.f;
    int e = e0;
    for (; e + 3 < e1; e += 4) {
        int s0 = esrc[e], s1 = esrc[e + 1], s2 = esrc[e + 2], s3 = esrc[e + 3];
        float w0 = aw2[e], w1 = aw2[e + 1], w2 = aw2[e + 2], w3 = aw2[e + 3];
        ushort4 u0 = *(const ushort4*)(hb + s0 * 64);
        ushort4 u1 = *(const ushort4*)(hb + s1 * 64);
        ushort4 u2 = *(const ushort4*)(hb + s2 * 64);
        ushort4 u3 = *(const ushort4*)(hb + s3 * 64);
        dn += (w0 + w1) + (w2 + w3);
        acc[0] = fmaf(w0, bf2f(u0.x), fmaf(w1, bf2f(u1.x), fmaf(w2, bf2f(u2.x), fmaf(w3, bf2f(u3.x), acc[0]))));
        acc[1] = fmaf(w0, bf2f(u0.y), fmaf(w1, bf2f(u1.y), fmaf(w2, bf2f(u2.y), fmaf(w3, bf2f(u3.y), acc[1]))));
        acc[2] = fmaf(w0, bf2f(u0.z), fmaf(w1, bf2f(u1.z), fmaf(w2, bf2f(u2.z), fmaf(w3, bf2f(u3.z), acc[2]))));
        acc[3] = fmaf(w0, bf2f(u0.w), fmaf(w1, bf2f(u1.w), fmaf(w2, bf2f(u2.w), fmaf(w3, bf2f(u3.w), acc[3]))));
    }
    for (; e < e1; ++e) {
        int s0 = esrc[e];
        float w0 = aw2[e];
        ushort4 u0 = *(const ushort4*)(hb + s0 * 64);
        dn += w0;
        acc[0] = fmaf(w0, bf2f(u0.x), acc[0]);
        acc[1] = fmaf(w0, bf2f(u0.y), acc[1]);
        acc[2] = fmaf(w0, bf2f(u0.z), acc[2]);
        acc[3] = fmaf(w0, bf2f(u0.w), acc[3]);
    }
    const float inv = 1.f / (dn + 1e-16f);
#pragma unroll
    for (int i = 0; i < 4; ++i) {
        int col = i * 16 + j2;                      // C2(j2*4+i)
        out[d * 64 + col] = acc[i] * inv + b2[col];
    }
}

// ---------------------------------------------------------------------------
// Workspace layout (bytes), total ~72.7 MB:
//   counts @ 0            200,000  [zeroed]
//   cursor @ 200,000      200,000  [zeroed]
//   off    @ 400,032      200,004
//   bsum   @ 600,064      800
//   as1    @ 600,896      800,000
//   ad1    @ 1,400,896    800,000
//   as2    @ 2,200,896    200,000
//   ad2    @ 2,400,896    200,000
//   esrc   @ 2,600,896    1,700,000  uint16
//   Wf1    @ 4,300,896    131,072
//   Wf2    @ 4,431,968    32,768
//   aw1    @ 4,464,736    13,600,000 f32 AoS [E_TOT][4]
//   h1b    @ 18,064,736   25,600,000 bf16 C1-perm (h2b reuses after gather1)
//   h2b    @ 18,064,736   6,400,000  bf16 C2-perm
//   hmid   @ 43,664,736   25,600,000 bf16 C1-perm
//   aw2    @ 69,264,736   3,400,000  f32
// ---------------------------------------------------------------------------
extern "C" void kernel_launch(void* const* d_in, const int* in_sizes, int n_in,
                              void* d_out, int out_size, void* d_ws, size_t ws_size,
                              hipStream_t stream)
{
    const float* x        = (const float*)d_in[0];
    const int*   ei       = (const int*)d_in[1];
    const float* W1       = (const float*)d_in[2];
    const float* att_src1 = (const float*)d_in[3];
    const float* att_dst1 = (const float*)d_in[4];
    const float* b1       = (const float*)d_in[5];
    const float* W2       = (const float*)d_in[6];
    const float* att_src2 = (const float*)d_in[7];
    const float* att_dst2 = (const float*)d_in[8];
    const float* b2       = (const float*)d_in[9];
    const int* src = ei;
    const int* dst = ei + E_RAW;
    float* out = (float*)d_out;

    char* ws = (char*)d_ws;
    int*            counts = (int*)(ws + 0);
    int*            cursor = (int*)(ws + 200000);
    int*            off    = (int*)(ws + 400032);
    int*            bsum   = (int*)(ws + 600064);
    float*          as1    = (float*)(ws + 600896);
    float*          ad1    = (float*)(ws + 1400896);
    float*          as2    = (float*)(ws + 2200896);
    float*          ad2    = (float*)(ws + 2400896);
    unsigned short* esrc   = (unsigned short*)(ws + 2600896);
    unsigned short* Wf1    = (unsigned short*)(ws + 4300896);
    unsigned short* Wf2    = (unsigned short*)(ws + 4431968);
    float*          aw1    = (float*)(ws + 4464736);
    unsigned short* h1b    = (unsigned short*)(ws + 18064736);
    unsigned short* h2b    = (unsigned short*)(ws + 18064736);  // reuses h1b
    unsigned short* hmid   = (unsigned short*)(ws + 43664736);
    float*          aw2    = (float*)(ws + 69264736);

    hipMemsetAsync(ws, 0, 400000, stream);      // counts + cursor

    const int EB = (E_TOT + 255) / 256;
    k_prep_hist<<<EB, 256, 0, stream>>>(dst, counts, W1, W2, Wf1, Wf2);
    k_scan1  <<<NBC, 256, 0, stream>>>(counts, off, bsum);
    k_scan2  <<<1, 256, 0, stream>>>(bsum);
    k_scan3  <<<NBC, 256, 0, stream>>>(off, bsum);
    k_gemm1  <<<3125, 256, 0, stream>>>(x, Wf1, att_src1, att_dst1, h1b, as1, ad1);
    k_scatter<<<EB, 256, 0, stream>>>(src, dst, off, cursor, as1, ad1, esrc, aw1);
    k_gather1<<<12500, 256, 0, stream>>>(esrc, off, aw1, h1b, b1, hmid);
    k_gemm2  <<<782, 256, 0, stream>>>(hmid, Wf2, att_src2, att_dst2, h2b, as2, ad2);
    k_alpha2 <<<12500, 256, 0, stream>>>(esrc, off, as2, ad2, aw2);
    k_gather2<<<3125, 256, 0, stream>>>(esrc, off, aw2, h2b, b2, out);
}

// Round 12
// 243.751 us; speedup vs baseline: 5.6627x; 1.0605x over previous
//
#include <hip/hip_runtime.h>
#include <math.h>

#define N_NODES 50000
#define E_RAW   800000
#define E_TOT   850000
#define NEG_SLOPE 0.2f
#define NBC 196   // scan blocks = ceil(50000/256)

typedef __attribute__((ext_vector_type(8))) short short8;
typedef __attribute__((ext_vector_type(4))) float f32x4;

__device__ __forceinline__ float lrelu(float v) {
    return v >= 0.f ? v : NEG_SLOPE * v;
}
__device__ __forceinline__ unsigned short f2bf(float f) {
    union { float f; unsigned u; } v; v.f = f;
    unsigned r = v.u + 0x7FFF + ((v.u >> 16) & 1);
    return (unsigned short)(r >> 16);
}
__device__ __forceinline__ float bf2f(unsigned short h) {
    union { unsigned u; float f; } v; v.u = ((unsigned)h) << 16;
    return v.f;
}
// h1b position p holds column C1(p) (16x16 transpose, self-inverse)
__device__ __forceinline__ int C1(int p) { return (p & 15) * 16 + (p >> 4); }
// h2b position p holds column C2(p)
__device__ __forceinline__ int C2(int p) { return (p & 3) * 16 + (p >> 2); }

// ---------------------------------------------------------------------------
// prep (weight frags) + histogram, fused.
// ---------------------------------------------------------------------------
__global__ __launch_bounds__(256) void k_prep_hist(
    const int* __restrict__ dst, int* __restrict__ counts,
    const float* __restrict__ W1, const float* __restrict__ W2,
    unsigned short* __restrict__ Wf1, unsigned short* __restrict__ Wf2)
{
    int idx = blockIdx.x * 256 + threadIdx.x;
    if (idx < 8192) {
        int lane = idx & 63, kb = (idx >> 6) & 7, nb = idx >> 9;
        int c = nb * 16 + (lane & 15);
        int k0 = kb * 32 + ((lane >> 4) & 3) * 8;
        short8 pk;
#pragma unroll
        for (int j = 0; j < 8; ++j)
            pk[j] = (short)f2bf(W1[(k0 + j) * 256 + c]);
        *(short8*)&Wf1[idx * 8] = pk;
    } else if (idx < 10240) {
        int i2 = idx - 8192;
        int lane = i2 & 63, kb = (i2 >> 6) & 7, nb = i2 >> 9;
        int c = nb * 16 + (lane & 15);
        int k0 = kb * 32 + ((lane >> 4) & 3) * 8;
        short8 pk;
#pragma unroll
        for (int j = 0; j < 8; ++j)
            pk[j] = (short)f2bf(W2[C1(k0 + j) * 64 + c]);
        *(short8*)&Wf2[i2 * 8] = pk;
    }
    if (idx < E_TOT) {
        int d = (idx < E_RAW) ? dst[idx] : idx - E_RAW;
        atomicAdd(&counts[d], 1);
    }
}

__global__ __launch_bounds__(256) void k_scan1(
    const int* __restrict__ counts, int* __restrict__ off, int* __restrict__ bsum)
{
    __shared__ int sh[256];
    int t = threadIdx.x, i = blockIdx.x * 256 + t;
    int c = (i < N_NODES) ? counts[i] : 0;
    sh[t] = c; __syncthreads();
    for (int ofs = 1; ofs < 256; ofs <<= 1) {
        int v = (t >= ofs) ? sh[t - ofs] : 0;
        __syncthreads(); sh[t] += v; __syncthreads();
    }
    if (i < N_NODES) off[i] = sh[t] - c;
    if (t == 255) bsum[blockIdx.x] = sh[255];
}

__global__ __launch_bounds__(256) void k_scan2(int* __restrict__ bsum)
{
    __shared__ int sh[256];
    int t = threadIdx.x;
    int c = (t < NBC) ? bsum[t] : 0;
    sh[t] = c; __syncthreads();
    for (int ofs = 1; ofs < 256; ofs <<= 1) {
        int v = (t >= ofs) ? sh[t - ofs] : 0;
        __syncthreads(); sh[t] += v; __syncthreads();
    }
    if (t < NBC) bsum[t] = sh[t] - c;
}

__global__ __launch_bounds__(256) void k_scan3(
    int* __restrict__ off, const int* __restrict__ bsum)
{
    int i = blockIdx.x * 256 + threadIdx.x;
    if (i < N_NODES) off[i] += bsum[blockIdx.x];
    if (i == 0) off[N_NODES] = E_TOT;
}

// ---------------------------------------------------------------------------
// scatter + layer-1 edge weights (AoS float4 at CSR position).
// ---------------------------------------------------------------------------
__global__ __launch_bounds__(256) void k_scatter(
    const int* __restrict__ src, const int* __restrict__ dst,
    const int* __restrict__ off, int* __restrict__ cursor,
    const float* __restrict__ as1, const float* __restrict__ ad1,
    unsigned short* __restrict__ esrc, float* __restrict__ aw1)
{
    int e = blockIdx.x * 256 + threadIdx.x;
    if (e >= E_TOT) return;
    int s, d;
    if (e < E_RAW) { s = src[e]; d = dst[e]; } else { s = e - E_RAW; d = s; }
    int pos = off[d] + atomicAdd(&cursor[d], 1);
    esrc[pos] = (unsigned short)s;
    float4 A = *(const float4*)&as1[s * 4];
    float4 B = *(const float4*)&ad1[d * 4];
    float4 w;
    w.x = __expf(lrelu(A.x + B.x));
    w.y = __expf(lrelu(A.y + B.y));
    w.z = __expf(lrelu(A.z + B.z));
    w.w = __expf(lrelu(A.w + B.w));
    *(float4*)&aw1[pos * 4] = w;
}

// ---------------------------------------------------------------------------
// GEMM1: h1 = x @ W1, MFMA 16x16x32. h1b stored C1-PERMUTED (8B stores).
// Fused att-dot epilogue. (r9, unchanged)
// ---------------------------------------------------------------------------
__global__ __launch_bounds__(256) void k_gemm1(
    const float* __restrict__ x, const unsigned short* __restrict__ Wf1,
    const float* __restrict__ att_src, const float* __restrict__ att_dst,
    unsigned short* __restrict__ h1b, float* __restrict__ as1, float* __restrict__ ad1)
{
    const int t = threadIdx.x;
    const int lane = t & 63;
    const int w = t >> 6;
    const int rbase = blockIdx.x * 16;
    const int q  = lane & 15;
    const int kg = lane >> 4;
    const int rowA = rbase + q;

    f32x4 acc[4];
#pragma unroll
    for (int nb = 0; nb < 4; ++nb) acc[nb] = (f32x4){0.f, 0.f, 0.f, 0.f};

    short8 b[2][4];
    float4 a0, a1, a0n, a1n;
    {
        const float* ap = &x[rowA * 256 + kg * 8];
        a0 = *(const float4*)ap;
        a1 = *(const float4*)(ap + 4);
#pragma unroll
        for (int nb = 0; nb < 4; ++nb)
            b[0][nb] = *(const short8*)&Wf1[(((w * 4 + nb) * 8 + 0) * 64 + lane) * 8];
    }
#pragma unroll
    for (int kb = 0; kb < 8; ++kb) {
        if (kb < 7) {
            const float* ap = &x[rowA * 256 + (kb + 1) * 32 + kg * 8];
            a0n = *(const float4*)ap;
            a1n = *(const float4*)(ap + 4);
#pragma unroll
            for (int nb = 0; nb < 4; ++nb)
                b[(kb + 1) & 1][nb] =
                    *(const short8*)&Wf1[(((w * 4 + nb) * 8 + kb + 1) * 64 + lane) * 8];
        }
        short8 af;
        af[0] = (short)f2bf(a0.x); af[1] = (short)f2bf(a0.y);
        af[2] = (short)f2bf(a0.z); af[3] = (short)f2bf(a0.w);
        af[4] = (short)f2bf(a1.x); af[5] = (short)f2bf(a1.y);
        af[6] = (short)f2bf(a1.z); af[7] = (short)f2bf(a1.w);
#pragma unroll
        for (int nb = 0; nb < 4; ++nb)
            acc[nb] = __builtin_amdgcn_mfma_f32_16x16x32_bf16(af, b[kb & 1][nb], acc[nb], 0, 0, 0);
        if (kb < 7) { a0 = a0n; a1 = a1n; }
    }

#pragma unroll
    for (int reg = 0; reg < 4; ++reg) {
        int n = rbase + kg * 4 + reg;
        ushort4 pk;
        pk.x = f2bf(acc[0][reg]); pk.y = f2bf(acc[1][reg]);
        pk.z = f2bf(acc[2][reg]); pk.w = f2bf(acc[3][reg]);
        *(ushort4*)&h1b[n * 256 + q * 16 + w * 4] = pk;   // C1-permuted, 8B
    }
    float asv[4], adv[4];
#pragma unroll
    for (int nb = 0; nb < 4; ++nb) {
        int col = (w * 4 + nb) * 16 + q;
        asv[nb] = att_src[col];
        adv[nb] = att_dst[col];
    }
#pragma unroll
    for (int reg = 0; reg < 4; ++reg) {
        float s = acc[0][reg]*asv[0] + acc[1][reg]*asv[1] + acc[2][reg]*asv[2] + acc[3][reg]*asv[3];
        float d = acc[0][reg]*adv[0] + acc[1][reg]*adv[1] + acc[2][reg]*adv[2] + acc[3][reg]*adv[3];
#pragma unroll
        for (int ofs = 1; ofs < 16; ofs <<= 1) {
            s += __shfl_xor(s, ofs);
            d += __shfl_xor(d, ofs);
        }
        if (q == 0) {
            int n = rbase + kg * 4 + reg;
            as1[n * 4 + w] = s;
            ad1[n * 4 + w] = d;
        }
    }
}

// ---------------------------------------------------------------------------
// FUSED gather1 + gemm2 + att2-dots. Block = 16 dst (3125 blocks exact).
// Phase 1: wave w runs the r9 gather body for dsts d0+w*4..+3 serially,
//   writing each finished row (bias+ELU, bf16, C1-permuted positions) into
//   LDS hs[16][264] (264 = 256+8 pad -> phase-2 ds_read_b128 2-way free).
// Phase 2: wave w computes h2 cols w*16..+15 for all 16 rows: 8 MFMAs with
//   A-frags from LDS and the nb=w slice of Wf2 (k-axis pre-permuted by C1,
//   matching the LDS rows' position order). h2b stored C2-permuted. att2
//   partial dots reduced across waves via tiny LDS.
// Saves the 25.6 MB hmid write + 25.6 MB read + a kernel launch vs r9.
// ---------------------------------------------------------------------------
__global__ __launch_bounds__(256) void k_gat1g2(
    const unsigned short* __restrict__ esrc, const int* __restrict__ off,
    const float* __restrict__ aw1,
    const unsigned short* __restrict__ h1b, const float* __restrict__ b1,
    const unsigned short* __restrict__ Wf2,
    const float* __restrict__ att_src2, const float* __restrict__ att_dst2,
    unsigned short* __restrict__ h2b, float* __restrict__ as2, float* __restrict__ ad2)
{
    __shared__ unsigned short hs[16][264];
    __shared__ float ss[16][4], sd[16][4];
    const int t = threadIdx.x;
    const int w = t >> 6;
    const int lane = t & 63;
    const int d0 = blockIdx.x * 16;
    const int head = lane & 3;

    // ---- phase 1: gather (r9 body), 4 dsts per wave ----
    for (int r = 0; r < 4; ++r) {
        const int ld = w * 4 + r;
        const int d = d0 + ld;
        const int e0 = off[d], e1 = off[d + 1];
        float4 acc = make_float4(0.f, 0.f, 0.f, 0.f);
        float dn = 0.f;
        int e = e0;
        for (; e + 3 < e1; e += 4) {
            int s0 = esrc[e], s1 = esrc[e + 1], s2 = esrc[e + 2], s3 = esrc[e + 3];
            float w0 = aw1[(e + 0) * 4 + head], w1 = aw1[(e + 1) * 4 + head];
            float w2 = aw1[(e + 2) * 4 + head], w3 = aw1[(e + 3) * 4 + head];
            ushort4 u0 = *(const ushort4*)&h1b[s0 * 256 + lane * 4];
            ushort4 u1 = *(const ushort4*)&h1b[s1 * 256 + lane * 4];
            ushort4 u2 = *(const ushort4*)&h1b[s2 * 256 + lane * 4];
            ushort4 u3 = *(const ushort4*)&h1b[s3 * 256 + lane * 4];
            dn += (w0 + w1) + (w2 + w3);
            acc.x = fmaf(w0, bf2f(u0.x), fmaf(w1, bf2f(u1.x), fmaf(w2, bf2f(u2.x), fmaf(w3, bf2f(u3.x), acc.x))));
            acc.y = fmaf(w0, bf2f(u0.y), fmaf(w1, bf2f(u1.y), fmaf(w2, bf2f(u2.y), fmaf(w3, bf2f(u3.y), acc.y))));
            acc.z = fmaf(w0, bf2f(u0.z), fmaf(w1, bf2f(u1.z), fmaf(w2, bf2f(u2.z), fmaf(w3, bf2f(u3.z), acc.z))));
            acc.w = fmaf(w0, bf2f(u0.w), fmaf(w1, bf2f(u1.w), fmaf(w2, bf2f(u2.w), fmaf(w3, bf2f(u3.w), acc.w))));
        }
        for (; e < e1; ++e) {
            int s0 = esrc[e];
            float w0 = aw1[e * 4 + head];
            ushort4 u0 = *(const ushort4*)&h1b[s0 * 256 + lane * 4];
            dn += w0;
            acc.x = fmaf(w0, bf2f(u0.x), acc.x);
            acc.y = fmaf(w0, bf2f(u0.y), acc.y);
            acc.z = fmaf(w0, bf2f(u0.z), acc.z);
            acc.w = fmaf(w0, bf2f(u0.w), acc.w);
        }
        const float inv = 1.f / (dn + 1e-16f);
        float o[4] = {acc.x, acc.y, acc.z, acc.w};
        ushort4 pk;
        unsigned short* pko = (unsigned short*)&pk;
#pragma unroll
        for (int i = 0; i < 4; ++i) {
            float v = o[i] * inv + b1[C1(lane * 4 + i)];
            v = v > 0.f ? v : expm1f(v);
            pko[i] = f2bf(v);
        }
        *(ushort4*)&hs[ld][lane * 4] = pk;
    }
    __syncthreads();

    // ---- phase 2: gemm2 cols w*16..+15 for the 16 rows ----
    const int q  = lane & 15;
    const int kg = lane >> 4;
    f32x4 acc2 = (f32x4){0.f, 0.f, 0.f, 0.f};
#pragma unroll
    for (int kb = 0; kb < 8; ++kb) {
        short8 af = *(const short8*)&hs[q][kb * 32 + kg * 8];
        short8 bf = *(const short8*)&Wf2[((w * 8 + kb) * 64 + lane) * 8];
        acc2 = __builtin_amdgcn_mfma_f32_16x16x32_bf16(af, bf, acc2, 0, 0, 0);
    }
    const float asv = att_src2[w * 16 + q];
    const float adv = att_dst2[w * 16 + q];
#pragma unroll
    for (int reg = 0; reg < 4; ++reg) {
        int row = kg * 4 + reg;
        int n = d0 + row;
        h2b[n * 64 + q * 4 + w] = f2bf(acc2[reg]);   // C2-perm: pos q*4+w = col w*16+q
        float s = acc2[reg] * asv;
        float d = acc2[reg] * adv;
#pragma unroll
        for (int ofs = 1; ofs < 16; ofs <<= 1) {
            s += __shfl_xor(s, ofs);
            d += __shfl_xor(d, ofs);
        }
        if (q == 0) { ss[row][w] = s; sd[row][w] = d; }
    }
    __syncthreads();
    if (t < 16) {
        as2[d0 + t] = (ss[t][0] + ss[t][1]) + (ss[t][2] + ss[t][3]);
        ad2[d0 + t] = (sd[t][0] + sd[t][1]) + (sd[t][2] + sd[t][3]);
    }
}

// ---------------------------------------------------------------------------
// gather2: 4 dst per wave (16-lane group owns ushort4 = 128B row), 4x unroll,
// inline exp. Writes d_out (un-permuting C2). (r9, unchanged)
// ---------------------------------------------------------------------------
__global__ __launch_bounds__(256) void k_gather2(
    const unsigned short* __restrict__ esrc, const int* __restrict__ off,
    const float* __restrict__ as2, const float* __restrict__ ad2,
    const unsigned short* __restrict__ h2b, const float* __restrict__ b2,
    float* __restrict__ out)
{
    const int t = threadIdx.x;
    const int w = t >> 6;
    const int lane = t & 63;
    const int g  = lane >> 4;
    const int j2 = lane & 15;
    const int d = blockIdx.x * 16 + w * 4 + g;      // 3125*16 = 50000 exact
    const float adv = ad2[d];
    const int e0 = off[d], e1 = off[d + 1];
    const unsigned short* hb = h2b + j2 * 4;

    float acc[4] = {0.f, 0.f, 0.f, 0.f};
    float dn = 0.f;
    int e = e0;
    for (; e + 3 < e1; e += 4) {
        int s0 = esrc[e], s1 = esrc[e + 1], s2 = esrc[e + 2], s3 = esrc[e + 3];
        float w0 = __expf(lrelu(as2[s0] + adv));
        float w1 = __expf(lrelu(as2[s1] + adv));
        float w2 = __expf(lrelu(as2[s2] + adv));
        float w3 = __expf(lrelu(as2[s3] + adv));
        ushort4 u0 = *(const ushort4*)(hb + s0 * 64);
        ushort4 u1 = *(const ushort4*)(hb + s1 * 64);
        ushort4 u2 = *(const ushort4*)(hb + s2 * 64);
        ushort4 u3 = *(const ushort4*)(hb + s3 * 64);
        dn += (w0 + w1) + (w2 + w3);
        acc[0] = fmaf(w0, bf2f(u0.x), fmaf(w1, bf2f(u1.x), fmaf(w2, bf2f(u2.x), fmaf(w3, bf2f(u3.x), acc[0]))));
        acc[1] = fmaf(w0, bf2f(u0.y), fmaf(w1, bf2f(u1.y), fmaf(w2, bf2f(u2.y), fmaf(w3, bf2f(u3.y), acc[1]))));
        acc[2] = fmaf(w0, bf2f(u0.z), fmaf(w1, bf2f(u1.z), fmaf(w2, bf2f(u2.z), fmaf(w3, bf2f(u3.z), acc[2]))));
        acc[3] = fmaf(w0, bf2f(u0.w), fmaf(w1, bf2f(u1.w), fmaf(w2, bf2f(u2.w), fmaf(w3, bf2f(u3.w), acc[3]))));
    }
    for (; e < e1; ++e) {
        int s0 = esrc[e];
        float w0 = __expf(lrelu(as2[s0] + adv));
        ushort4 u0 = *(const ushort4*)(hb + s0 * 64);
        dn += w0;
        acc[0] = fmaf(w0, bf2f(u0.x), acc[0]);
        acc[1] = fmaf(w0, bf2f(u0.y), acc[1]);
        acc[2] = fmaf(w0, bf2f(u0.z), acc[2]);
        acc[3] = fmaf(w0, bf2f(u0.w), acc[3]);
    }
    const float inv = 1.f / (dn + 1e-16f);
#pragma unroll
    for (int i = 0; i < 4; ++i) {
        int col = i * 16 + j2;                      // C2(j2*4+i)
        out[d * 64 + col] = acc[i] * inv + b2[col];
    }
}

// ---------------------------------------------------------------------------
// Workspace layout (bytes), total ~50.1 MB:
//   counts @ 0            200,000  [zeroed]
//   cursor @ 200,000      200,000  [zeroed]
//   off    @ 400,032      200,004
//   bsum   @ 600,064      800
//   as1    @ 600,896      800,000
//   ad1    @ 1,400,896    800,000
//   as2    @ 2,200,896    200,000
//   ad2    @ 2,400,896    200,000
//   esrc   @ 2,600,896    1,700,000  uint16
//   Wf1    @ 4,300,896    131,072
//   Wf2    @ 4,431,968    32,768
//   aw1    @ 4,464,736    13,600,000 f32 AoS [E_TOT][4]
//   h1b    @ 18,064,736   25,600,000 bf16 C1-perm
//   h2b    @ 43,664,736   6,400,000  bf16 C2-perm (separate: written while
//                                    h1b still being read in fused kernel)
// ---------------------------------------------------------------------------
extern "C" void kernel_launch(void* const* d_in, const int* in_sizes, int n_in,
                              void* d_out, int out_size, void* d_ws, size_t ws_size,
                              hipStream_t stream)
{
    const float* x        = (const float*)d_in[0];
    const int*   ei       = (const int*)d_in[1];
    const float* W1       = (const float*)d_in[2];
    const float* att_src1 = (const float*)d_in[3];
    const float* att_dst1 = (const float*)d_in[4];
    const float* b1       = (const float*)d_in[5];
    const float* W2       = (const float*)d_in[6];
    const float* att_src2 = (const float*)d_in[7];
    const float* att_dst2 = (const float*)d_in[8];
    const float* b2       = (const float*)d_in[9];
    const int* src = ei;
    const int* dst = ei + E_RAW;
    float* out = (float*)d_out;

    char* ws = (char*)d_ws;
    int*            counts = (int*)(ws + 0);
    int*            cursor = (int*)(ws + 200000);
    int*            off    = (int*)(ws + 400032);
    int*            bsum   = (int*)(ws + 600064);
    float*          as1    = (float*)(ws + 600896);
    float*          ad1    = (float*)(ws + 1400896);
    float*          as2    = (float*)(ws + 2200896);
    float*          ad2    = (float*)(ws + 2400896);
    unsigned short* esrc   = (unsigned short*)(ws + 2600896);
    unsigned short* Wf1    = (unsigned short*)(ws + 4300896);
    unsigned short* Wf2    = (unsigned short*)(ws + 4431968);
    float*          aw1    = (float*)(ws + 4464736);
    unsigned short* h1b    = (unsigned short*)(ws + 18064736);
    unsigned short* h2b    = (unsigned short*)(ws + 43664736);

    hipMemsetAsync(ws, 0, 400000, stream);      // counts + cursor

    const int EB = (E_TOT + 255) / 256;
    k_prep_hist<<<EB, 256, 0, stream>>>(dst, counts, W1, W2, Wf1, Wf2);
    k_scan1  <<<NBC, 256, 0, stream>>>(counts, off, bsum);
    k_scan2  <<<1, 256, 0, stream>>>(bsum);
    k_scan3  <<<NBC, 256, 0, stream>>>(off, bsum);
    k_gemm1  <<<3125, 256, 0, stream>>>(x, Wf1, att_src1, att_dst1, h1b, as1, ad1);
    k_scatter<<<EB, 256, 0, stream>>>(src, dst, off, cursor, as1, ad1, esrc, aw1);
    k_gat1g2 <<<3125, 256, 0, stream>>>(esrc, off, aw1, h1b, b1, Wf2,
                                        att_src2, att_dst2, h2b, as2, ad2);
    k_gather2<<<3125, 256, 0, stream>>>(esrc, off, as2, ad2, h2b, b2, out);
}

// Round 13
// 242.590 us; speedup vs baseline: 5.6898x; 1.0048x over previous
//
#include <hip/hip_runtime.h>
#include <math.h>

#define N_NODES 50000
#define E_RAW   800000
#define E_TOT   850000
#define NEG_SLOPE 0.2f
#define NBC 196   // scan blocks = ceil(50000/256)

typedef __attribute__((ext_vector_type(8))) short short8;
typedef __attribute__((ext_vector_type(4))) float f32x4;

__device__ __forceinline__ float lrelu(float v) {
    return v >= 0.f ? v : NEG_SLOPE * v;
}
__device__ __forceinline__ unsigned short f2bf(float f) {
    union { float f; unsigned u; } v; v.f = f;
    unsigned r = v.u + 0x7FFF + ((v.u >> 16) & 1);
    return (unsigned short)(r >> 16);
}
__device__ __forceinline__ float bf2f(unsigned short h) {
    union { unsigned u; float f; } v; v.u = ((unsigned)h) << 16;
    return v.f;
}
// h1b position p holds column C1(p) (16x16 transpose, self-inverse)
__device__ __forceinline__ int C1(int p) { return (p & 15) * 16 + (p >> 4); }
// h2b position p holds column C2(p)
__device__ __forceinline__ int C2(int p) { return (p & 3) * 16 + (p >> 2); }

// ---------------------------------------------------------------------------
// prep (weight frags) + histogram, fused.
// ---------------------------------------------------------------------------
__global__ __launch_bounds__(256) void k_prep_hist(
    const int* __restrict__ dst, int* __restrict__ counts,
    const float* __restrict__ W1, const float* __restrict__ W2,
    unsigned short* __restrict__ Wf1, unsigned short* __restrict__ Wf2)
{
    int idx = blockIdx.x * 256 + threadIdx.x;
    if (idx < 8192) {
        int lane = idx & 63, kb = (idx >> 6) & 7, nb = idx >> 9;
        int c = nb * 16 + (lane & 15);
        int k0 = kb * 32 + ((lane >> 4) & 3) * 8;
        short8 pk;
#pragma unroll
        for (int j = 0; j < 8; ++j)
            pk[j] = (short)f2bf(W1[(k0 + j) * 256 + c]);
        *(short8*)&Wf1[idx * 8] = pk;
    } else if (idx < 10240) {
        int i2 = idx - 8192;
        int lane = i2 & 63, kb = (i2 >> 6) & 7, nb = i2 >> 9;
        int c = nb * 16 + (lane & 15);
        int k0 = kb * 32 + ((lane >> 4) & 3) * 8;
        short8 pk;
#pragma unroll
        for (int j = 0; j < 8; ++j)
            pk[j] = (short)f2bf(W2[C1(k0 + j) * 64 + c]);
        *(short8*)&Wf2[i2 * 8] = pk;
    }
    if (idx < E_TOT) {
        int d = (idx < E_RAW) ? dst[idx] : idx - E_RAW;
        atomicAdd(&counts[d], 1);
    }
}

__global__ __launch_bounds__(256) void k_scan1(
    const int* __restrict__ counts, int* __restrict__ off, int* __restrict__ bsum)
{
    __shared__ int sh[256];
    int t = threadIdx.x, i = blockIdx.x * 256 + t;
    int c = (i < N_NODES) ? counts[i] : 0;
    sh[t] = c; __syncthreads();
    for (int ofs = 1; ofs < 256; ofs <<= 1) {
        int v = (t >= ofs) ? sh[t - ofs] : 0;
        __syncthreads(); sh[t] += v; __syncthreads();
    }
    if (i < N_NODES) off[i] = sh[t] - c;
    if (t == 255) bsum[blockIdx.x] = sh[255];
}

__global__ __launch_bounds__(256) void k_scan2(int* __restrict__ bsum)
{
    __shared__ int sh[256];
    int t = threadIdx.x;
    int c = (t < NBC) ? bsum[t] : 0;
    sh[t] = c; __syncthreads();
    for (int ofs = 1; ofs < 256; ofs <<= 1) {
        int v = (t >= ofs) ? sh[t - ofs] : 0;
        __syncthreads(); sh[t] += v; __syncthreads();
    }
    if (t < NBC) bsum[t] = sh[t] - c;
}

__global__ __launch_bounds__(256) void k_scan3(
    int* __restrict__ off, const int* __restrict__ bsum)
{
    int i = blockIdx.x * 256 + threadIdx.x;
    if (i < N_NODES) off[i] += bsum[blockIdx.x];
    if (i == 0) off[N_NODES] = E_TOT;
}

// ---------------------------------------------------------------------------
// scatter: CSR position + esrc (uint16) only. No weight compute (r13: inline
// weights in the gather beat the precompute+stream — r5 vs r9 evidence).
// ---------------------------------------------------------------------------
__global__ __launch_bounds__(256) void k_scatter(
    const int* __restrict__ src, const int* __restrict__ dst,
    const int* __restrict__ off, int* __restrict__ cursor,
    unsigned short* __restrict__ esrc)
{
    int e = blockIdx.x * 256 + threadIdx.x;
    if (e >= E_TOT) return;
    int s, d;
    if (e < E_RAW) { s = src[e]; d = dst[e]; } else { s = e - E_RAW; d = s; }
    int pos = off[d] + atomicAdd(&cursor[d], 1);
    esrc[pos] = (unsigned short)s;
}

// ---------------------------------------------------------------------------
// GEMM1: h1 = x @ W1, MFMA 16x16x32. h1b stored C1-PERMUTED (8B stores).
// Fused att-dot epilogue. (r9, unchanged)
// ---------------------------------------------------------------------------
__global__ __launch_bounds__(256) void k_gemm1(
    const float* __restrict__ x, const unsigned short* __restrict__ Wf1,
    const float* __restrict__ att_src, const float* __restrict__ att_dst,
    unsigned short* __restrict__ h1b, float* __restrict__ as1, float* __restrict__ ad1)
{
    const int t = threadIdx.x;
    const int lane = t & 63;
    const int w = t >> 6;
    const int rbase = blockIdx.x * 16;
    const int q  = lane & 15;
    const int kg = lane >> 4;
    const int rowA = rbase + q;

    f32x4 acc[4];
#pragma unroll
    for (int nb = 0; nb < 4; ++nb) acc[nb] = (f32x4){0.f, 0.f, 0.f, 0.f};

    short8 b[2][4];
    float4 a0, a1, a0n, a1n;
    {
        const float* ap = &x[rowA * 256 + kg * 8];
        a0 = *(const float4*)ap;
        a1 = *(const float4*)(ap + 4);
#pragma unroll
        for (int nb = 0; nb < 4; ++nb)
            b[0][nb] = *(const short8*)&Wf1[(((w * 4 + nb) * 8 + 0) * 64 + lane) * 8];
    }
#pragma unroll
    for (int kb = 0; kb < 8; ++kb) {
        if (kb < 7) {
            const float* ap = &x[rowA * 256 + (kb + 1) * 32 + kg * 8];
            a0n = *(const float4*)ap;
            a1n = *(const float4*)(ap + 4);
#pragma unroll
            for (int nb = 0; nb < 4; ++nb)
                b[(kb + 1) & 1][nb] =
                    *(const short8*)&Wf1[(((w * 4 + nb) * 8 + kb + 1) * 64 + lane) * 8];
        }
        short8 af;
        af[0] = (short)f2bf(a0.x); af[1] = (short)f2bf(a0.y);
        af[2] = (short)f2bf(a0.z); af[3] = (short)f2bf(a0.w);
        af[4] = (short)f2bf(a1.x); af[5] = (short)f2bf(a1.y);
        af[6] = (short)f2bf(a1.z); af[7] = (short)f2bf(a1.w);
#pragma unroll
        for (int nb = 0; nb < 4; ++nb)
            acc[nb] = __builtin_amdgcn_mfma_f32_16x16x32_bf16(af, b[kb & 1][nb], acc[nb], 0, 0, 0);
        if (kb < 7) { a0 = a0n; a1 = a1n; }
    }

#pragma unroll
    for (int reg = 0; reg < 4; ++reg) {
        int n = rbase + kg * 4 + reg;
        ushort4 pk;
        pk.x = f2bf(acc[0][reg]); pk.y = f2bf(acc[1][reg]);
        pk.z = f2bf(acc[2][reg]); pk.w = f2bf(acc[3][reg]);
        *(ushort4*)&h1b[n * 256 + q * 16 + w * 4] = pk;   // C1-permuted, 8B
    }
    float asv[4], adv[4];
#pragma unroll
    for (int nb = 0; nb < 4; ++nb) {
        int col = (w * 4 + nb) * 16 + q;
        asv[nb] = att_src[col];
        adv[nb] = att_dst[col];
    }
#pragma unroll
    for (int reg = 0; reg < 4; ++reg) {
        float s = acc[0][reg]*asv[0] + acc[1][reg]*asv[1] + acc[2][reg]*asv[2] + acc[3][reg]*asv[3];
        float d = acc[0][reg]*adv[0] + acc[1][reg]*adv[1] + acc[2][reg]*adv[2] + acc[3][reg]*adv[3];
#pragma unroll
        for (int ofs = 1; ofs < 16; ofs <<= 1) {
            s += __shfl_xor(s, ofs);
            d += __shfl_xor(d, ofs);
        }
        if (q == 0) {
            int n = rbase + kg * 4 + reg;
            as1[n * 4 + w] = s;
            ad1[n * 4 + w] = d;
        }
    }
}

// ---------------------------------------------------------------------------
// FUSED gather1 + gemm2 + att2-dots. Block = 16 dst (3125 blocks exact).
// Phase 1: wave w runs the r5-style INLINE-weight gather for dsts
//   d0+w*4..+3 serially (per edge: as1[s*4+head] scalar + exp(lrelu)),
//   writing finished rows (bias+ELU, bf16, C1-permuted) into LDS hs[16][264].
// Phase 2: wave w computes h2 cols w*16..+15 for all 16 rows (8 MFMAs off
//   LDS + nb=w slice of Wf2, k-permuted). h2b C2-permuted; att2 dots via
//   16-lane shfl + LDS cross-wave reduce.
// ---------------------------------------------------------------------------
__global__ __launch_bounds__(256) void k_gat1g2(
    const unsigned short* __restrict__ esrc, const int* __restrict__ off,
    const float* __restrict__ as1, const float* __restrict__ ad1,
    const unsigned short* __restrict__ h1b, const float* __restrict__ b1,
    const unsigned short* __restrict__ Wf2,
    const float* __restrict__ att_src2, const float* __restrict__ att_dst2,
    unsigned short* __restrict__ h2b, float* __restrict__ as2, float* __restrict__ ad2)
{
    __shared__ unsigned short hs[16][264];
    __shared__ float ss[16][4], sd[16][4];
    const int t = threadIdx.x;
    const int w = t >> 6;
    const int lane = t & 63;
    const int d0 = blockIdx.x * 16;
    const int head = lane & 3;

    // ---- phase 1: gather (r5 inline-weight body), 4 dsts per wave ----
    for (int r = 0; r < 4; ++r) {
        const int ld = w * 4 + r;
        const int d = d0 + ld;
        const float adv = ad1[d * 4 + head];
        const int e0 = off[d], e1 = off[d + 1];
        float4 acc = make_float4(0.f, 0.f, 0.f, 0.f);
        float dn = 0.f;
        int e = e0;
        for (; e + 3 < e1; e += 4) {
            int s0 = esrc[e], s1 = esrc[e + 1], s2 = esrc[e + 2], s3 = esrc[e + 3];
            float w0 = __expf(lrelu(as1[s0 * 4 + head] + adv));
            float w1 = __expf(lrelu(as1[s1 * 4 + head] + adv));
            float w2 = __expf(lrelu(as1[s2 * 4 + head] + adv));
            float w3 = __expf(lrelu(as1[s3 * 4 + head] + adv));
            ushort4 u0 = *(const ushort4*)&h1b[s0 * 256 + lane * 4];
            ushort4 u1 = *(const ushort4*)&h1b[s1 * 256 + lane * 4];
            ushort4 u2 = *(const ushort4*)&h1b[s2 * 256 + lane * 4];
            ushort4 u3 = *(const ushort4*)&h1b[s3 * 256 + lane * 4];
            dn += (w0 + w1) + (w2 + w3);
            acc.x = fmaf(w0, bf2f(u0.x), fmaf(w1, bf2f(u1.x), fmaf(w2, bf2f(u2.x), fmaf(w3, bf2f(u3.x), acc.x))));
            acc.y = fmaf(w0, bf2f(u0.y), fmaf(w1, bf2f(u1.y), fmaf(w2, bf2f(u2.y), fmaf(w3, bf2f(u3.y), acc.y))));
            acc.z = fmaf(w0, bf2f(u0.z), fmaf(w1, bf2f(u1.z), fmaf(w2, bf2f(u2.z), fmaf(w3, bf2f(u3.z), acc.z))));
            acc.w = fmaf(w0, bf2f(u0.w), fmaf(w1, bf2f(u1.w), fmaf(w2, bf2f(u2.w), fmaf(w3, bf2f(u3.w), acc.w))));
        }
        for (; e < e1; ++e) {
            int s0 = esrc[e];
            float w0 = __expf(lrelu(as1[s0 * 4 + head] + adv));
            ushort4 u0 = *(const ushort4*)&h1b[s0 * 256 + lane * 4];
            dn += w0;
            acc.x = fmaf(w0, bf2f(u0.x), acc.x);
            acc.y = fmaf(w0, bf2f(u0.y), acc.y);
            acc.z = fmaf(w0, bf2f(u0.z), acc.z);
            acc.w = fmaf(w0, bf2f(u0.w), acc.w);
        }
        const float inv = 1.f / (dn + 1e-16f);
        float o[4] = {acc.x, acc.y, acc.z, acc.w};
        ushort4 pk;
        unsigned short* pko = (unsigned short*)&pk;
#pragma unroll
        for (int i = 0; i < 4; ++i) {
            float v = o[i] * inv + b1[C1(lane * 4 + i)];
            v = v > 0.f ? v : expm1f(v);
            pko[i] = f2bf(v);
        }
        *(ushort4*)&hs[ld][lane * 4] = pk;
    }
    __syncthreads();

    // ---- phase 2: gemm2 cols w*16..+15 for the 16 rows ----
    const int q  = lane & 15;
    const int kg = lane >> 4;
    f32x4 acc2 = (f32x4){0.f, 0.f, 0.f, 0.f};
#pragma unroll
    for (int kb = 0; kb < 8; ++kb) {
        short8 af = *(const short8*)&hs[q][kb * 32 + kg * 8];
        short8 bf = *(const short8*)&Wf2[((w * 8 + kb) * 64 + lane) * 8];
        acc2 = __builtin_amdgcn_mfma_f32_16x16x32_bf16(af, bf, acc2, 0, 0, 0);
    }
    const float asv = att_src2[w * 16 + q];
    const float adv = att_dst2[w * 16 + q];
#pragma unroll
    for (int reg = 0; reg < 4; ++reg) {
        int row = kg * 4 + reg;
        int n = d0 + row;
        h2b[n * 64 + q * 4 + w] = f2bf(acc2[reg]);   // C2-perm: pos q*4+w = col w*16+q
        float s = acc2[reg] * asv;
        float d = acc2[reg] * adv;
#pragma unroll
        for (int ofs = 1; ofs < 16; ofs <<= 1) {
            s += __shfl_xor(s, ofs);
            d += __shfl_xor(d, ofs);
        }
        if (q == 0) { ss[row][w] = s; sd[row][w] = d; }
    }
    __syncthreads();
    if (t < 16) {
        as2[d0 + t] = (ss[t][0] + ss[t][1]) + (ss[t][2] + ss[t][3]);
        ad2[d0 + t] = (sd[t][0] + sd[t][1]) + (sd[t][2] + sd[t][3]);
    }
}

// ---------------------------------------------------------------------------
// gather2: 4 dst per wave (16-lane group owns ushort4 = 128B row), 4x unroll,
// inline exp. Writes d_out (un-permuting C2). (r12, unchanged)
// ---------------------------------------------------------------------------
__global__ __launch_bounds__(256) void k_gather2(
    const unsigned short* __restrict__ esrc, const int* __restrict__ off,
    const float* __restrict__ as2, const float* __restrict__ ad2,
    const unsigned short* __restrict__ h2b, const float* __restrict__ b2,
    float* __restrict__ out)
{
    const int t = threadIdx.x;
    const int w = t >> 6;
    const int lane = t & 63;
    const int g  = lane >> 4;
    const int j2 = lane & 15;
    const int d = blockIdx.x * 16 + w * 4 + g;      // 3125*16 = 50000 exact
    const float adv = ad2[d];
    const int e0 = off[d], e1 = off[d + 1];
    const unsigned short* hb = h2b + j2 * 4;

    float acc[4] = {0.f, 0.f, 0.f, 0.f};
    float dn = 0.f;
    int e = e0;
    for (; e + 3 < e1; e += 4) {
        int s0 = esrc[e], s1 = esrc[e + 1], s2 = esrc[e + 2], s3 = esrc[e + 3];
        float w0 = __expf(lrelu(as2[s0] + adv));
        float w1 = __expf(lrelu(as2[s1] + adv));
        float w2 = __expf(lrelu(as2[s2] + adv));
        float w3 = __expf(lrelu(as2[s3] + adv));
        ushort4 u0 = *(const ushort4*)(hb + s0 * 64);
        ushort4 u1 = *(const ushort4*)(hb + s1 * 64);
        ushort4 u2 = *(const ushort4*)(hb + s2 * 64);
        ushort4 u3 = *(const ushort4*)(hb + s3 * 64);
        dn += (w0 + w1) + (w2 + w3);
        acc[0] = fmaf(w0, bf2f(u0.x), fmaf(w1, bf2f(u1.x), fmaf(w2, bf2f(u2.x), fmaf(w3, bf2f(u3.x), acc[0]))));
        acc[1] = fmaf(w0, bf2f(u0.y), fmaf(w1, bf2f(u1.y), fmaf(w2, bf2f(u2.y), fmaf(w3, bf2f(u3.y), acc[1]))));
        acc[2] = fmaf(w0, bf2f(u0.z), fmaf(w1, bf2f(u1.z), fmaf(w2, bf2f(u2.z), fmaf(w3, bf2f(u3.z), acc[2]))));
        acc[3] = fmaf(w0, bf2f(u0.w), fmaf(w1, bf2f(u1.w), fmaf(w2, bf2f(u2.w), fmaf(w3, bf2f(u3.w), acc[3]))));
    }
    for (; e < e1; ++e) {
        int s0 = esrc[e];
        float w0 = __expf(lrelu(as2[s0] + adv));
        ushort4 u0 = *(const ushort4*)(hb + s0 * 64);
        dn += w0;
        acc[0] = fmaf(w0, bf2f(u0.x), acc[0]);
        acc[1] = fmaf(w0, bf2f(u0.y), acc[1]);
        acc[2] = fmaf(w0, bf2f(u0.z), acc[2]);
        acc[3] = fmaf(w0, bf2f(u0.w), acc[3]);
    }
    const float inv = 1.f / (dn + 1e-16f);
#pragma unroll
    for (int i = 0; i < 4; ++i) {
        int col = i * 16 + j2;                      // C2(j2*4+i)
        out[d * 64 + col] = acc[i] * inv + b2[col];
    }
}

// ---------------------------------------------------------------------------
// Workspace layout (bytes), total ~36.5 MB:
//   counts @ 0            200,000  [zeroed]
//   cursor @ 200,000      200,000  [zeroed]
//   off    @ 400,032      200,004
//   bsum   @ 600,064      800
//   as1    @ 600,896      800,000
//   ad1    @ 1,400,896    800,000
//   as2    @ 2,200,896    200,000
//   ad2    @ 2,400,896    200,000
//   esrc   @ 2,600,896    1,700,000  uint16
//   Wf1    @ 4,300,896    131,072
//   Wf2    @ 4,431,968    32,768
//   h1b    @ 4,464,736    25,600,000 bf16 C1-perm
//   h2b    @ 30,064,736   6,400,000  bf16 C2-perm
// ---------------------------------------------------------------------------
extern "C" void kernel_launch(void* const* d_in, const int* in_sizes, int n_in,
                              void* d_out, int out_size, void* d_ws, size_t ws_size,
                              hipStream_t stream)
{
    const float* x        = (const float*)d_in[0];
    const int*   ei       = (const int*)d_in[1];
    const float* W1       = (const float*)d_in[2];
    const float* att_src1 = (const float*)d_in[3];
    const float* att_dst1 = (const float*)d_in[4];
    const float* b1       = (const float*)d_in[5];
    const float* W2       = (const float*)d_in[6];
    const float* att_src2 = (const float*)d_in[7];
    const float* att_dst2 = (const float*)d_in[8];
    const float* b2       = (const float*)d_in[9];
    const int* src = ei;
    const int* dst = ei + E_RAW;
    float* out = (float*)d_out;

    char* ws = (char*)d_ws;
    int*            counts = (int*)(ws + 0);
    int*            cursor = (int*)(ws + 200000);
    int*            off    = (int*)(ws + 400032);
    int*            bsum   = (int*)(ws + 600064);
    float*          as1    = (float*)(ws + 600896);
    float*          ad1    = (float*)(ws + 1400896);
    float*          as2    = (float*)(ws + 2200896);
    float*          ad2    = (float*)(ws + 2400896);
    unsigned short* esrc   = (unsigned short*)(ws + 2600896);
    unsigned short* Wf1    = (unsigned short*)(ws + 4300896);
    unsigned short* Wf2    = (unsigned short*)(ws + 4431968);
    unsigned short* h1b    = (unsigned short*)(ws + 4464736);
    unsigned short* h2b    = (unsigned short*)(ws + 30064736);

    hipMemsetAsync(ws, 0, 400000, stream);      // counts + cursor

    const int EB = (E_TOT + 255) / 256;
    k_prep_hist<<<EB, 256, 0, stream>>>(dst, counts, W1, W2, Wf1, Wf2);
    k_scan1  <<<NBC, 256, 0, stream>>>(counts, off, bsum);
    k_scan2  <<<1, 256, 0, stream>>>(bsum);
    k_scan3  <<<NBC, 256, 0, stream>>>(off, bsum);
    k_scatter<<<EB, 256, 0, stream>>>(src, dst, off, cursor, esrc);
    k_gemm1  <<<3125, 256, 0, stream>>>(x, Wf1, att_src1, att_dst1, h1b, as1, ad1);
    k_gat1g2 <<<3125, 256, 0, stream>>>(esrc, off, as1, ad1, h1b, b1, Wf2,
                                        att_src2, att_dst2, h2b, as2, ad2);
    k_gather2<<<3125, 256, 0, stream>>>(esrc, off, as2, ad2, h2b, b2, out);
}

// Round 14
// 234.244 us; speedup vs baseline: 5.8925x; 1.0356x over previous
//
#include <hip/hip_runtime.h>
#include <math.h>

#define N_NODES 50000
#define E_RAW   800000
#define E_TOT   850000
#define NEG_SLOPE 0.2f
#define NBC 196        // scan blocks = ceil(50000/256)
#define GEMM1_BLKS 3125
#define SCAT_BLKS  3321  // ceil(850000/256)

typedef __attribute__((ext_vector_type(8))) short short8;
typedef __attribute__((ext_vector_type(4))) float f32x4;

__device__ __forceinline__ float lrelu(float v) {
    return v >= 0.f ? v : NEG_SLOPE * v;
}
__device__ __forceinline__ unsigned short f2bf(float f) {
    union { float f; unsigned u; } v; v.f = f;
    unsigned r = v.u + 0x7FFF + ((v.u >> 16) & 1);
    return (unsigned short)(r >> 16);
}
__device__ __forceinline__ float bf2f(unsigned short h) {
    union { unsigned u; float f; } v; v.u = ((unsigned)h) << 16;
    return v.f;
}
// h1b position p holds column C1(p) (16x16 transpose, self-inverse)
__device__ __forceinline__ int C1(int p) { return (p & 15) * 16 + (p >> 4); }
// h2b position p holds column C2(p)
__device__ __forceinline__ int C2(int p) { return (p & 3) * 16 + (p >> 2); }

// ---------------------------------------------------------------------------
// prep (weight frags) + histogram, fused.
// ---------------------------------------------------------------------------
__global__ __launch_bounds__(256) void k_prep_hist(
    const int* __restrict__ dst, int* __restrict__ counts,
    const float* __restrict__ W1, const float* __restrict__ W2,
    unsigned short* __restrict__ Wf1, unsigned short* __restrict__ Wf2)
{
    int idx = blockIdx.x * 256 + threadIdx.x;
    if (idx < 8192) {
        int lane = idx & 63, kb = (idx >> 6) & 7, nb = idx >> 9;
        int c = nb * 16 + (lane & 15);
        int k0 = kb * 32 + ((lane >> 4) & 3) * 8;
        short8 pk;
#pragma unroll
        for (int j = 0; j < 8; ++j)
            pk[j] = (short)f2bf(W1[(k0 + j) * 256 + c]);
        *(short8*)&Wf1[idx * 8] = pk;
    } else if (idx < 10240) {
        int i2 = idx - 8192;
        int lane = i2 & 63, kb = (i2 >> 6) & 7, nb = i2 >> 9;
        int c = nb * 16 + (lane & 15);
        int k0 = kb * 32 + ((lane >> 4) & 3) * 8;
        short8 pk;
#pragma unroll
        for (int j = 0; j < 8; ++j)
            pk[j] = (short)f2bf(W2[C1(k0 + j) * 64 + c]);
        *(short8*)&Wf2[i2 * 8] = pk;
    }
    if (idx < E_TOT) {
        int d = (idx < E_RAW) ? dst[idx] : idx - E_RAW;
        atomicAdd(&counts[d], 1);
    }
}

// ---------------------------------------------------------------------------
// scan1: per-block exclusive scan of counts; bsum[b] = block total.
// ---------------------------------------------------------------------------
__global__ __launch_bounds__(256) void k_scan1(
    const int* __restrict__ counts, int* __restrict__ off, int* __restrict__ bsum)
{
    __shared__ int sh[256];
    int t = threadIdx.x, i = blockIdx.x * 256 + t;
    int c = (i < N_NODES) ? counts[i] : 0;
    sh[t] = c; __syncthreads();
    for (int ofs = 1; ofs < 256; ofs <<= 1) {
        int v = (t >= ofs) ? sh[t - ofs] : 0;
        __syncthreads(); sh[t] += v; __syncthreads();
    }
    if (i < N_NODES) off[i] = sh[t] - c;
    if (t == 255) bsum[blockIdx.x] = sh[255];
}

// ---------------------------------------------------------------------------
// scan23 (merged): block b computes base = sum(bsum[0..b-1]) itself via a
// 256-wide LDS reduce (NBC=196 <= 256), then adds it to its off chunk.
// ---------------------------------------------------------------------------
__global__ __launch_bounds__(256) void k_scan23(
    int* __restrict__ off, const int* __restrict__ bsum)
{
    __shared__ int sh[256];
    int t = threadIdx.x, b = blockIdx.x;
    sh[t] = (t < b) ? bsum[t] : 0;       // b <= 195 < 256
    __syncthreads();
    for (int ofs = 128; ofs > 0; ofs >>= 1) {
        if (t < ofs) sh[t] += sh[t + ofs];
        __syncthreads();
    }
    int base = sh[0];
    int i = b * 256 + t;
    if (i < N_NODES) off[i] += base;
    if (b == 0 && t == 0) off[N_NODES] = E_TOT;
}

// ---------------------------------------------------------------------------
// FUSED gemm1 + scatter. Blocks [0,3125): GEMM1 (r9 body, unchanged).
// Blocks [3125, 3125+3321): scatter — CSR position via atomicSub on counts
// (histogram still intact after scan1; pos = off[d]+old-1), esrc uint16.
// The two are independent once scans are done; fusing saves a launch and
// overlaps scatter's atomics under gemm1's memory latency.
// ---------------------------------------------------------------------------
__global__ __launch_bounds__(256) void k_gemm1_scatter(
    const float* __restrict__ x, const unsigned short* __restrict__ Wf1,
    const float* __restrict__ att_src, const float* __restrict__ att_dst,
    unsigned short* __restrict__ h1b, float* __restrict__ as1, float* __restrict__ ad1,
    const int* __restrict__ src, const int* __restrict__ dst,
    const int* __restrict__ off, int* __restrict__ counts,
    unsigned short* __restrict__ esrc)
{
    if (blockIdx.x >= GEMM1_BLKS) {
        int e = (blockIdx.x - GEMM1_BLKS) * 256 + threadIdx.x;
        if (e < E_TOT) {
            int s, d;
            if (e < E_RAW) { s = src[e]; d = dst[e]; } else { s = e - E_RAW; d = s; }
            int old = atomicSub(&counts[d], 1);
            esrc[off[d] + old - 1] = (unsigned short)s;
        }
        return;
    }
    const int t = threadIdx.x;
    const int lane = t & 63;
    const int w = t >> 6;
    const int rbase = blockIdx.x * 16;
    const int q  = lane & 15;
    const int kg = lane >> 4;
    const int rowA = rbase + q;

    f32x4 acc[4];
#pragma unroll
    for (int nb = 0; nb < 4; ++nb) acc[nb] = (f32x4){0.f, 0.f, 0.f, 0.f};

    short8 b[2][4];
    float4 a0, a1, a0n, a1n;
    {
        const float* ap = &x[rowA * 256 + kg * 8];
        a0 = *(const float4*)ap;
        a1 = *(const float4*)(ap + 4);
#pragma unroll
        for (int nb = 0; nb < 4; ++nb)
            b[0][nb] = *(const short8*)&Wf1[(((w * 4 + nb) * 8 + 0) * 64 + lane) * 8];
    }
#pragma unroll
    for (int kb = 0; kb < 8; ++kb) {
        if (kb < 7) {
            const float* ap = &x[rowA * 256 + (kb + 1) * 32 + kg * 8];
            a0n = *(const float4*)ap;
            a1n = *(const float4*)(ap + 4);
#pragma unroll
            for (int nb = 0; nb < 4; ++nb)
                b[(kb + 1) & 1][nb] =
                    *(const short8*)&Wf1[(((w * 4 + nb) * 8 + kb + 1) * 64 + lane) * 8];
        }
        short8 af;
        af[0] = (short)f2bf(a0.x); af[1] = (short)f2bf(a0.y);
        af[2] = (short)f2bf(a0.z); af[3] = (short)f2bf(a0.w);
        af[4] = (short)f2bf(a1.x); af[5] = (short)f2bf(a1.y);
        af[6] = (short)f2bf(a1.z); af[7] = (short)f2bf(a1.w);
#pragma unroll
        for (int nb = 0; nb < 4; ++nb)
            acc[nb] = __builtin_amdgcn_mfma_f32_16x16x32_bf16(af, b[kb & 1][nb], acc[nb], 0, 0, 0);
        if (kb < 7) { a0 = a0n; a1 = a1n; }
    }

#pragma unroll
    for (int reg = 0; reg < 4; ++reg) {
        int n = rbase + kg * 4 + reg;
        ushort4 pk;
        pk.x = f2bf(acc[0][reg]); pk.y = f2bf(acc[1][reg]);
        pk.z = f2bf(acc[2][reg]); pk.w = f2bf(acc[3][reg]);
        *(ushort4*)&h1b[n * 256 + q * 16 + w * 4] = pk;   // C1-permuted, 8B
    }
    float asv[4], adv[4];
#pragma unroll
    for (int nb = 0; nb < 4; ++nb) {
        int col = (w * 4 + nb) * 16 + q;
        asv[nb] = att_src[col];
        adv[nb] = att_dst[col];
    }
#pragma unroll
    for (int reg = 0; reg < 4; ++reg) {
        float s = acc[0][reg]*asv[0] + acc[1][reg]*asv[1] + acc[2][reg]*asv[2] + acc[3][reg]*asv[3];
        float d = acc[0][reg]*adv[0] + acc[1][reg]*adv[1] + acc[2][reg]*adv[2] + acc[3][reg]*adv[3];
#pragma unroll
        for (int ofs = 1; ofs < 16; ofs <<= 1) {
            s += __shfl_xor(s, ofs);
            d += __shfl_xor(d, ofs);
        }
        if (q == 0) {
            int n = rbase + kg * 4 + reg;
            as1[n * 4 + w] = s;
            ad1[n * 4 + w] = d;
        }
    }
}

// ---------------------------------------------------------------------------
// FUSED gather1 + gemm2 + att2-dots. Block = 16 dst (3125 blocks exact).
// (r13, unchanged)
// ---------------------------------------------------------------------------
__global__ __launch_bounds__(256) void k_gat1g2(
    const unsigned short* __restrict__ esrc, const int* __restrict__ off,
    const float* __restrict__ as1, const float* __restrict__ ad1,
    const unsigned short* __restrict__ h1b, const float* __restrict__ b1,
    const unsigned short* __restrict__ Wf2,
    const float* __restrict__ att_src2, const float* __restrict__ att_dst2,
    unsigned short* __restrict__ h2b, float* __restrict__ as2, float* __restrict__ ad2)
{
    __shared__ unsigned short hs[16][264];
    __shared__ float ss[16][4], sd[16][4];
    const int t = threadIdx.x;
    const int w = t >> 6;
    const int lane = t & 63;
    const int d0 = blockIdx.x * 16;
    const int head = lane & 3;

    // ---- phase 1: gather (inline-weight body), 4 dsts per wave ----
    for (int r = 0; r < 4; ++r) {
        const int ld = w * 4 + r;
        const int d = d0 + ld;
        const float adv = ad1[d * 4 + head];
        const int e0 = off[d], e1 = off[d + 1];
        float4 acc = make_float4(0.f, 0.f, 0.f, 0.f);
        float dn = 0.f;
        int e = e0;
        for (; e + 3 < e1; e += 4) {
            int s0 = esrc[e], s1 = esrc[e + 1], s2 = esrc[e + 2], s3 = esrc[e + 3];
            float w0 = __expf(lrelu(as1[s0 * 4 + head] + adv));
            float w1 = __expf(lrelu(as1[s1 * 4 + head] + adv));
            float w2 = __expf(lrelu(as1[s2 * 4 + head] + adv));
            float w3 = __expf(lrelu(as1[s3 * 4 + head] + adv));
            ushort4 u0 = *(const ushort4*)&h1b[s0 * 256 + lane * 4];
            ushort4 u1 = *(const ushort4*)&h1b[s1 * 256 + lane * 4];
            ushort4 u2 = *(const ushort4*)&h1b[s2 * 256 + lane * 4];
            ushort4 u3 = *(const ushort4*)&h1b[s3 * 256 + lane * 4];
            dn += (w0 + w1) + (w2 + w3);
            acc.x = fmaf(w0, bf2f(u0.x), fmaf(w1, bf2f(u1.x), fmaf(w2, bf2f(u2.x), fmaf(w3, bf2f(u3.x), acc.x))));
            acc.y = fmaf(w0, bf2f(u0.y), fmaf(w1, bf2f(u1.y), fmaf(w2, bf2f(u2.y), fmaf(w3, bf2f(u3.y), acc.y))));
            acc.z = fmaf(w0, bf2f(u0.z), fmaf(w1, bf2f(u1.z), fmaf(w2, bf2f(u2.z), fmaf(w3, bf2f(u3.z), acc.z))));
            acc.w = fmaf(w0, bf2f(u0.w), fmaf(w1, bf2f(u1.w), fmaf(w2, bf2f(u2.w), fmaf(w3, bf2f(u3.w), acc.w))));
        }
        for (; e < e1; ++e) {
            int s0 = esrc[e];
            float w0 = __expf(lrelu(as1[s0 * 4 + head] + adv));
            ushort4 u0 = *(const ushort4*)&h1b[s0 * 256 + lane * 4];
            dn += w0;
            acc.x = fmaf(w0, bf2f(u0.x), acc.x);
            acc.y = fmaf(w0, bf2f(u0.y), acc.y);
            acc.z = fmaf(w0, bf2f(u0.z), acc.z);
            acc.w = fmaf(w0, bf2f(u0.w), acc.w);
        }
        const float inv = 1.f / (dn + 1e-16f);
        float o[4] = {acc.x, acc.y, acc.z, acc.w};
        ushort4 pk;
        unsigned short* pko = (unsigned short*)&pk;
#pragma unroll
        for (int i = 0; i < 4; ++i) {
            float v = o[i] * inv + b1[C1(lane * 4 + i)];
            v = v > 0.f ? v : expm1f(v);
            pko[i] = f2bf(v);
        }
        *(ushort4*)&hs[ld][lane * 4] = pk;
    }
    __syncthreads();

    // ---- phase 2: gemm2 cols w*16..+15 for the 16 rows ----
    const int q  = lane & 15;
    const int kg = lane >> 4;
    f32x4 acc2 = (f32x4){0.f, 0.f, 0.f, 0.f};
#pragma unroll
    for (int kb = 0; kb < 8; ++kb) {
        short8 af = *(const short8*)&hs[q][kb * 32 + kg * 8];
        short8 bf = *(const short8*)&Wf2[((w * 8 + kb) * 64 + lane) * 8];
        acc2 = __builtin_amdgcn_mfma_f32_16x16x32_bf16(af, bf, acc2, 0, 0, 0);
    }
    const float asv = att_src2[w * 16 + q];
    const float adv = att_dst2[w * 16 + q];
#pragma unroll
    for (int reg = 0; reg < 4; ++reg) {
        int row = kg * 4 + reg;
        int n = d0 + row;
        h2b[n * 64 + q * 4 + w] = f2bf(acc2[reg]);   // C2-perm: pos q*4+w = col w*16+q
        float s = acc2[reg] * asv;
        float d = acc2[reg] * adv;
#pragma unroll
        for (int ofs = 1; ofs < 16; ofs <<= 1) {
            s += __shfl_xor(s, ofs);
            d += __shfl_xor(d, ofs);
        }
        if (q == 0) { ss[row][w] = s; sd[row][w] = d; }
    }
    __syncthreads();
    if (t < 16) {
        as2[d0 + t] = (ss[t][0] + ss[t][1]) + (ss[t][2] + ss[t][3]);
        ad2[d0 + t] = (sd[t][0] + sd[t][1]) + (sd[t][2] + sd[t][3]);
    }
}

// ---------------------------------------------------------------------------
// gather2: 4 dst per wave (16-lane group owns ushort4 = 128B row), 4x unroll,
// inline exp. Writes d_out (un-permuting C2). (r12, unchanged)
// ---------------------------------------------------------------------------
__global__ __launch_bounds__(256) void k_gather2(
    const unsigned short* __restrict__ esrc, const int* __restrict__ off,
    const float* __restrict__ as2, const float* __restrict__ ad2,
    const unsigned short* __restrict__ h2b, const float* __restrict__ b2,
    float* __restrict__ out)
{
    const int t = threadIdx.x;
    const int w = t >> 6;
    const int lane = t & 63;
    const int g  = lane >> 4;
    const int j2 = lane & 15;
    const int d = blockIdx.x * 16 + w * 4 + g;      // 3125*16 = 50000 exact
    const float adv = ad2[d];
    const int e0 = off[d], e1 = off[d + 1];
    const unsigned short* hb = h2b + j2 * 4;

    float acc[4] = {0.f, 0.f, 0.f, 0.f};
    float dn = 0.f;
    int e = e0;
    for (; e + 3 < e1; e += 4) {
        int s0 = esrc[e], s1 = esrc[e + 1], s2 = esrc[e + 2], s3 = esrc[e + 3];
        float w0 = __expf(lrelu(as2[s0] + adv));
        float w1 = __expf(lrelu(as2[s1] + adv));
        float w2 = __expf(lrelu(as2[s2] + adv));
        float w3 = __expf(lrelu(as2[s3] + adv));
        ushort4 u0 = *(const ushort4*)(hb + s0 * 64);
        ushort4 u1 = *(const ushort4*)(hb + s1 * 64);
        ushort4 u2 = *(const ushort4*)(hb + s2 * 64);
        ushort4 u3 = *(const ushort4*)(hb + s3 * 64);
        dn += (w0 + w1) + (w2 + w3);
        acc[0] = fmaf(w0, bf2f(u0.x), fmaf(w1, bf2f(u1.x), fmaf(w2, bf2f(u2.x), fmaf(w3, bf2f(u3.x), acc[0]))));
        acc[1] = fmaf(w0, bf2f(u0.y), fmaf(w1, bf2f(u1.y), fmaf(w2, bf2f(u2.y), fmaf(w3, bf2f(u3.y), acc[1]))));
        acc[2] = fmaf(w0, bf2f(u0.z), fmaf(w1, bf2f(u1.z), fmaf(w2, bf2f(u2.z), fmaf(w3, bf2f(u3.z), acc[2]))));
        acc[3] = fmaf(w0, bf2f(u0.w), fmaf(w1, bf2f(u1.w), fmaf(w2, bf2f(u2.w), fmaf(w3, bf2f(u3.w), acc[3]))));
    }
    for (; e < e1; ++e) {
        int s0 = esrc[e];
        float w0 = __expf(lrelu(as2[s0] + adv));
        ushort4 u0 = *(const ushort4*)(hb + s0 * 64);
        dn += w0;
        acc[0] = fmaf(w0, bf2f(u0.x), acc[0]);
        acc[1] = fmaf(w0, bf2f(u0.y), acc[1]);
        acc[2] = fmaf(w0, bf2f(u0.z), acc[2]);
        acc[3] = fmaf(w0, bf2f(u0.w), acc[3]);
    }
    const float inv = 1.f / (dn + 1e-16f);
#pragma unroll
    for (int i = 0; i < 4; ++i) {
        int col = i * 16 + j2;                      // C2(j2*4+i)
        out[d * 64 + col] = acc[i] * inv + b2[col];
    }
}

// ---------------------------------------------------------------------------
// Workspace layout (bytes), total ~36.3 MB:
//   counts @ 0            200,000  [zeroed; consumed as cursor by scatter]
//   off    @ 200,000      200,004
//   bsum   @ 400,032      800
//   as1    @ 400,896      800,000
//   ad1    @ 1,200,896    800,000
//   as2    @ 2,000,896    200,000
//   ad2    @ 2,200,896    200,000
//   esrc   @ 2,400,896    1,700,000  uint16
//   Wf1    @ 4,100,896    131,072
//   Wf2    @ 4,231,968    32,768
//   h1b    @ 4,264,736    25,600,000 bf16 C1-perm
//   h2b    @ 29,864,736   6,400,000  bf16 C2-perm
// ---------------------------------------------------------------------------
extern "C" void kernel_launch(void* const* d_in, const int* in_sizes, int n_in,
                              void* d_out, int out_size, void* d_ws, size_t ws_size,
                              hipStream_t stream)
{
    const float* x        = (const float*)d_in[0];
    const int*   ei       = (const int*)d_in[1];
    const float* W1       = (const float*)d_in[2];
    const float* att_src1 = (const float*)d_in[3];
    const float* att_dst1 = (const float*)d_in[4];
    const float* b1       = (const float*)d_in[5];
    const float* W2       = (const float*)d_in[6];
    const float* att_src2 = (const float*)d_in[7];
    const float* att_dst2 = (const float*)d_in[8];
    const float* b2       = (const float*)d_in[9];
    const int* src = ei;
    const int* dst = ei + E_RAW;
    float* out = (float*)d_out;

    char* ws = (char*)d_ws;
    int*            counts = (int*)(ws + 0);
    int*            off    = (int*)(ws + 200000);
    int*            bsum   = (int*)(ws + 400032);
    float*          as1    = (float*)(ws + 400896);
    float*          ad1    = (float*)(ws + 1200896);
    float*          as2    = (float*)(ws + 2000896);
    float*          ad2    = (float*)(ws + 2200896);
    unsigned short* esrc   = (unsigned short*)(ws + 2400896);
    unsigned short* Wf1    = (unsigned short*)(ws + 4100896);
    unsigned short* Wf2    = (unsigned short*)(ws + 4231968);
    unsigned short* h1b    = (unsigned short*)(ws + 4264736);
    unsigned short* h2b    = (unsigned short*)(ws + 29864736);

    hipMemsetAsync(counts, 0, 200000, stream);

    const int EB = (E_TOT + 255) / 256;
    k_prep_hist<<<EB, 256, 0, stream>>>(dst, counts, W1, W2, Wf1, Wf2);
    k_scan1  <<<NBC, 256, 0, stream>>>(counts, off, bsum);
    k_scan23 <<<NBC, 256, 0, stream>>>(off, bsum);
    k_gemm1_scatter<<<GEMM1_BLKS + SCAT_BLKS, 256, 0, stream>>>(
        x, Wf1, att_src1, att_dst1, h1b, as1, ad1,
        src, dst, off, counts, esrc);
    k_gat1g2 <<<3125, 256, 0, stream>>>(esrc, off, as1, ad1, h1b, b1, Wf2,
                                        att_src2, att_dst2, h2b, as2, ad2);
    k_gather2<<<3125, 256, 0, stream>>>(esrc, off, as2, ad2, h2b, b2, out);
}

// Round 15
// 222.566 us; speedup vs baseline: 6.2017x; 1.0525x over previous
//
#include <hip/hip_runtime.h>
#include <math.h>

#define N_NODES 50000
#define E_RAW   800000
#define E_TOT   850000
#define NEG_SLOPE 0.2f
#define NBC 196        // scan blocks = ceil(50000/256)
#define G1_BLKS 782    // ceil(50000/64)
#define SCAT_BLKS 3321 // ceil(850000/256)

typedef __attribute__((ext_vector_type(8))) short short8;
typedef __attribute__((ext_vector_type(4))) float f32x4;

__device__ __forceinline__ float lrelu(float v) {
    return v >= 0.f ? v : NEG_SLOPE * v;
}
__device__ __forceinline__ unsigned short f2bf(float f) {
    union { float f; unsigned u; } v; v.f = f;
    unsigned r = v.u + 0x7FFF + ((v.u >> 16) & 1);
    return (unsigned short)(r >> 16);
}
__device__ __forceinline__ float bf2f(unsigned short h) {
    union { unsigned u; float f; } v; v.u = ((unsigned)h) << 16;
    return v.f;
}
// h1b position p holds column C1(p) (16x16 transpose, self-inverse)
__device__ __forceinline__ int C1(int p) { return (p & 15) * 16 + (p >> 4); }
// h2b position p holds column C2(p)
__device__ __forceinline__ int C2(int p) { return (p & 3) * 16 + (p >> 2); }

// ---------------------------------------------------------------------------
// prep (weight frags) + histogram, fused.
// ---------------------------------------------------------------------------
__global__ __launch_bounds__(256) void k_prep_hist(
    const int* __restrict__ dst, int* __restrict__ counts,
    const float* __restrict__ W1, const float* __restrict__ W2,
    unsigned short* __restrict__ Wf1, unsigned short* __restrict__ Wf2)
{
    int idx = blockIdx.x * 256 + threadIdx.x;
    if (idx < 8192) {
        int lane = idx & 63, kb = (idx >> 6) & 7, nb = idx >> 9;
        int c = nb * 16 + (lane & 15);
        int k0 = kb * 32 + ((lane >> 4) & 3) * 8;
        short8 pk;
#pragma unroll
        for (int j = 0; j < 8; ++j)
            pk[j] = (short)f2bf(W1[(k0 + j) * 256 + c]);
        *(short8*)&Wf1[idx * 8] = pk;
    } else if (idx < 10240) {
        int i2 = idx - 8192;
        int lane = i2 & 63, kb = (i2 >> 6) & 7, nb = i2 >> 9;
        int c = nb * 16 + (lane & 15);
        int k0 = kb * 32 + ((lane >> 4) & 3) * 8;
        short8 pk;
#pragma unroll
        for (int j = 0; j < 8; ++j)
            pk[j] = (short)f2bf(W2[C1(k0 + j) * 64 + c]);
        *(short8*)&Wf2[i2 * 8] = pk;
    }
    if (idx < E_TOT) {
        int d = (idx < E_RAW) ? dst[idx] : idx - E_RAW;
        atomicAdd(&counts[d], 1);
    }
}

// ---------------------------------------------------------------------------
// scan1: per-block exclusive scan of counts; bsum[b] = block total.
// ---------------------------------------------------------------------------
__global__ __launch_bounds__(256) void k_scan1(
    const int* __restrict__ counts, int* __restrict__ off, int* __restrict__ bsum)
{
    __shared__ int sh[256];
    int t = threadIdx.x, i = blockIdx.x * 256 + t;
    int c = (i < N_NODES) ? counts[i] : 0;
    sh[t] = c; __syncthreads();
    for (int ofs = 1; ofs < 256; ofs <<= 1) {
        int v = (t >= ofs) ? sh[t - ofs] : 0;
        __syncthreads(); sh[t] += v; __syncthreads();
    }
    if (i < N_NODES) off[i] = sh[t] - c;
    if (t == 255) bsum[blockIdx.x] = sh[255];
}

// ---------------------------------------------------------------------------
// scan23 (merged): block b computes base = sum(bsum[0..b-1]) via LDS reduce.
// ---------------------------------------------------------------------------
__global__ __launch_bounds__(256) void k_scan23(
    int* __restrict__ off, const int* __restrict__ bsum)
{
    __shared__ int sh[256];
    int t = threadIdx.x, b = blockIdx.x;
    sh[t] = (t < b) ? bsum[t] : 0;       // b <= 195 < 256
    __syncthreads();
    for (int ofs = 128; ofs > 0; ofs >>= 1) {
        if (t < ofs) sh[t] += sh[t + ofs];
        __syncthreads();
    }
    int base = sh[0];
    int i = b * 256 + t;
    if (i < N_NODES) off[i] += base;
    if (b == 0 && t == 0) off[N_NODES] = E_TOT;
}

// ---------------------------------------------------------------------------
// FUSED gemm1 + scatter.
// Blocks [0, G1_BLKS): GEMM1 with LDS-staged coalesced A.
//   Stage 64 rows x 256 f32 -> bf16 LDS [64][264] (coalesced float4 loads),
//   then wave w (= head w, nb w*4..+3) runs 8 kb: 4 B-frags (Wf1, L2) +
//   4 row-groups { ds_read A-frag, 4 MFMA }. 16 acc frags (f32x4) per lane.
//   h1b stored C1-permuted (8B stores); fused att-dot epilogue per rg.
// Blocks [G1_BLKS, +SCAT_BLKS): scatter via atomicSub on counts.
// ---------------------------------------------------------------------------
__global__ __launch_bounds__(256) void k_gemm1_scatter(
    const float* __restrict__ x, const unsigned short* __restrict__ Wf1,
    const float* __restrict__ att_src, const float* __restrict__ att_dst,
    unsigned short* __restrict__ h1b, float* __restrict__ as1, float* __restrict__ ad1,
    const int* __restrict__ src, const int* __restrict__ dst,
    const int* __restrict__ off, int* __restrict__ counts,
    unsigned short* __restrict__ esrc)
{
    if (blockIdx.x >= G1_BLKS) {
        int e = (blockIdx.x - G1_BLKS) * 256 + threadIdx.x;
        if (e < E_TOT) {
            int s, d;
            if (e < E_RAW) { s = src[e]; d = dst[e]; } else { s = e - E_RAW; d = s; }
            int old = atomicSub(&counts[d], 1);
            esrc[off[d] + old - 1] = (unsigned short)s;
        }
        return;
    }
    __shared__ unsigned short hsx[64 * 264];
    const int t = threadIdx.x;
    const int rbase = blockIdx.x * 64;

    // ---- stage x tile (coalesced) ----
#pragma unroll
    for (int it = 0; it < 16; ++it) {
        int idx = it * 1024 + t * 4;
        int row = idx >> 8, col = idx & 255;
        int rA = rbase + row;
        if (rA >= N_NODES) rA = N_NODES - 1;
        float4 v = *(const float4*)&x[rA * 256 + col];
        ushort4 pk;
        pk.x = f2bf(v.x); pk.y = f2bf(v.y); pk.z = f2bf(v.z); pk.w = f2bf(v.w);
        *(ushort4*)&hsx[row * 264 + col] = pk;
    }
    __syncthreads();

    const int lane = t & 63;
    const int w = t >> 6;           // wave = head = nb group
    const int q  = lane & 15;
    const int kg = lane >> 4;

    f32x4 acc[4][4];                // [rg][nb]
#pragma unroll
    for (int rg = 0; rg < 4; ++rg)
#pragma unroll
        for (int nb = 0; nb < 4; ++nb) acc[rg][nb] = (f32x4){0.f, 0.f, 0.f, 0.f};

#pragma unroll
    for (int kb = 0; kb < 8; ++kb) {
        short8 b[4];
#pragma unroll
        for (int nb = 0; nb < 4; ++nb)
            b[nb] = *(const short8*)&Wf1[(((w * 4 + nb) * 8 + kb) * 64 + lane) * 8];
#pragma unroll
        for (int rg = 0; rg < 4; ++rg) {
            short8 af = *(const short8*)&hsx[(rg * 16 + q) * 264 + kb * 32 + kg * 8];
#pragma unroll
            for (int nb = 0; nb < 4; ++nb)
                acc[rg][nb] = __builtin_amdgcn_mfma_f32_16x16x32_bf16(af, b[nb], acc[rg][nb], 0, 0, 0);
        }
    }

    float asv[4], adv[4];
#pragma unroll
    for (int nb = 0; nb < 4; ++nb) {
        int col = (w * 4 + nb) * 16 + q;
        asv[nb] = att_src[col];
        adv[nb] = att_dst[col];
    }
#pragma unroll
    for (int rg = 0; rg < 4; ++rg) {
#pragma unroll
        for (int reg = 0; reg < 4; ++reg) {
            int n = rbase + rg * 16 + kg * 4 + reg;
            bool ok = n < N_NODES;
            if (ok) {
                ushort4 pk;
                pk.x = f2bf(acc[rg][0][reg]); pk.y = f2bf(acc[rg][1][reg]);
                pk.z = f2bf(acc[rg][2][reg]); pk.w = f2bf(acc[rg][3][reg]);
                *(ushort4*)&h1b[n * 256 + q * 16 + w * 4] = pk;   // C1-perm, 8B
            }
            float s = acc[rg][0][reg]*asv[0] + acc[rg][1][reg]*asv[1]
                    + acc[rg][2][reg]*asv[2] + acc[rg][3][reg]*asv[3];
            float d = acc[rg][0][reg]*adv[0] + acc[rg][1][reg]*adv[1]
                    + acc[rg][2][reg]*adv[2] + acc[rg][3][reg]*adv[3];
#pragma unroll
            for (int ofs = 1; ofs < 16; ofs <<= 1) {
                s += __shfl_xor(s, ofs);
                d += __shfl_xor(d, ofs);
            }
            if (ok && q == 0) {
                as1[n * 4 + w] = s;
                ad1[n * 4 + w] = d;
            }
        }
    }
}

// ---------------------------------------------------------------------------
// FUSED gather1 + gemm2 + att2-dots. Block = 16 dst (3125 blocks exact).
// (r13, unchanged)
// ---------------------------------------------------------------------------
__global__ __launch_bounds__(256) void k_gat1g2(
    const unsigned short* __restrict__ esrc, const int* __restrict__ off,
    const float* __restrict__ as1, const float* __restrict__ ad1,
    const unsigned short* __restrict__ h1b, const float* __restrict__ b1,
    const unsigned short* __restrict__ Wf2,
    const float* __restrict__ att_src2, const float* __restrict__ att_dst2,
    unsigned short* __restrict__ h2b, float* __restrict__ as2, float* __restrict__ ad2)
{
    __shared__ unsigned short hs[16][264];
    __shared__ float ss[16][4], sd[16][4];
    const int t = threadIdx.x;
    const int w = t >> 6;
    const int lane = t & 63;
    const int d0 = blockIdx.x * 16;
    const int head = lane & 3;

    // ---- phase 1: gather (inline-weight body), 4 dsts per wave ----
    for (int r = 0; r < 4; ++r) {
        const int ld = w * 4 + r;
        const int d = d0 + ld;
        const float adv = ad1[d * 4 + head];
        const int e0 = off[d], e1 = off[d + 1];
        float4 acc = make_float4(0.f, 0.f, 0.f, 0.f);
        float dn = 0.f;
        int e = e0;
        for (; e + 3 < e1; e += 4) {
            int s0 = esrc[e], s1 = esrc[e + 1], s2 = esrc[e + 2], s3 = esrc[e + 3];
            float w0 = __expf(lrelu(as1[s0 * 4 + head] + adv));
            float w1 = __expf(lrelu(as1[s1 * 4 + head] + adv));
            float w2 = __expf(lrelu(as1[s2 * 4 + head] + adv));
            float w3 = __expf(lrelu(as1[s3 * 4 + head] + adv));
            ushort4 u0 = *(const ushort4*)&h1b[s0 * 256 + lane * 4];
            ushort4 u1 = *(const ushort4*)&h1b[s1 * 256 + lane * 4];
            ushort4 u2 = *(const ushort4*)&h1b[s2 * 256 + lane * 4];
            ushort4 u3 = *(const ushort4*)&h1b[s3 * 256 + lane * 4];
            dn += (w0 + w1) + (w2 + w3);
            acc.x = fmaf(w0, bf2f(u0.x), fmaf(w1, bf2f(u1.x), fmaf(w2, bf2f(u2.x), fmaf(w3, bf2f(u3.x), acc.x))));
            acc.y = fmaf(w0, bf2f(u0.y), fmaf(w1, bf2f(u1.y), fmaf(w2, bf2f(u2.y), fmaf(w3, bf2f(u3.y), acc.y))));
            acc.z = fmaf(w0, bf2f(u0.z), fmaf(w1, bf2f(u1.z), fmaf(w2, bf2f(u2.z), fmaf(w3, bf2f(u3.z), acc.z))));
            acc.w = fmaf(w0, bf2f(u0.w), fmaf(w1, bf2f(u1.w), fmaf(w2, bf2f(u2.w), fmaf(w3, bf2f(u3.w), acc.w))));
        }
        for (; e < e1; ++e) {
            int s0 = esrc[e];
            float w0 = __expf(lrelu(as1[s0 * 4 + head] + adv));
            ushort4 u0 = *(const ushort4*)&h1b[s0 * 256 + lane * 4];
            dn += w0;
            acc.x = fmaf(w0, bf2f(u0.x), acc.x);
            acc.y = fmaf(w0, bf2f(u0.y), acc.y);
            acc.z = fmaf(w0, bf2f(u0.z), acc.z);
            acc.w = fmaf(w0, bf2f(u0.w), acc.w);
        }
        const float inv = 1.f / (dn + 1e-16f);
        float o[4] = {acc.x, acc.y, acc.z, acc.w};
        ushort4 pk;
        unsigned short* pko = (unsigned short*)&pk;
#pragma unroll
        for (int i = 0; i < 4; ++i) {
            float v = o[i] * inv + b1[C1(lane * 4 + i)];
            v = v > 0.f ? v : expm1f(v);
            pko[i] = f2bf(v);
        }
        *(ushort4*)&hs[ld][lane * 4] = pk;
    }
    __syncthreads();

    // ---- phase 2: gemm2 cols w*16..+15 for the 16 rows ----
    const int q  = lane & 15;
    const int kg = lane >> 4;
    f32x4 acc2 = (f32x4){0.f, 0.f, 0.f, 0.f};
#pragma unroll
    for (int kb = 0; kb < 8; ++kb) {
        short8 af = *(const short8*)&hs[q][kb * 32 + kg * 8];
        short8 bf = *(const short8*)&Wf2[((w * 8 + kb) * 64 + lane) * 8];
        acc2 = __builtin_amdgcn_mfma_f32_16x16x32_bf16(af, bf, acc2, 0, 0, 0);
    }
    const float asv = att_src2[w * 16 + q];
    const float adv = att_dst2[w * 16 + q];
#pragma unroll
    for (int reg = 0; reg < 4; ++reg) {
        int row = kg * 4 + reg;
        int n = d0 + row;
        h2b[n * 64 + q * 4 + w] = f2bf(acc2[reg]);   // C2-perm: pos q*4+w = col w*16+q
        float s = acc2[reg] * asv;
        float d = acc2[reg] * adv;
#pragma unroll
        for (int ofs = 1; ofs < 16; ofs <<= 1) {
            s += __shfl_xor(s, ofs);
            d += __shfl_xor(d, ofs);
        }
        if (q == 0) { ss[row][w] = s; sd[row][w] = d; }
    }
    __syncthreads();
    if (t < 16) {
        as2[d0 + t] = (ss[t][0] + ss[t][1]) + (ss[t][2] + ss[t][3]);
        ad2[d0 + t] = (sd[t][0] + sd[t][1]) + (sd[t][2] + sd[t][3]);
    }
}

// ---------------------------------------------------------------------------
// gather2: 4 dst per wave (16-lane group owns ushort4 = 128B row), 4x unroll,
// inline exp. Writes d_out (un-permuting C2). (r12, unchanged)
// ---------------------------------------------------------------------------
__global__ __launch_bounds__(256) void k_gather2(
    const unsigned short* __restrict__ esrc, const int* __restrict__ off,
    const float* __restrict__ as2, const float* __restrict__ ad2,
    const unsigned short* __restrict__ h2b, const float* __restrict__ b2,
    float* __restrict__ out)
{
    const int t = threadIdx.x;
    const int w = t >> 6;
    const int lane = t & 63;
    const int g  = lane >> 4;
    const int j2 = lane & 15;
    const int d = blockIdx.x * 16 + w * 4 + g;      // 3125*16 = 50000 exact
    const float adv = ad2[d];
    const int e0 = off[d], e1 = off[d + 1];
    const unsigned short* hb = h2b + j2 * 4;

    float acc[4] = {0.f, 0.f, 0.f, 0.f};
    float dn = 0.f;
    int e = e0;
    for (; e + 3 < e1; e += 4) {
        int s0 = esrc[e], s1 = esrc[e + 1], s2 = esrc[e + 2], s3 = esrc[e + 3];
        float w0 = __expf(lrelu(as2[s0] + adv));
        float w1 = __expf(lrelu(as2[s1] + adv));
        float w2 = __expf(lrelu(as2[s2] + adv));
        float w3 = __expf(lrelu(as2[s3] + adv));
        ushort4 u0 = *(const ushort4*)(hb + s0 * 64);
        ushort4 u1 = *(const ushort4*)(hb + s1 * 64);
        ushort4 u2 = *(const ushort4*)(hb + s2 * 64);
        ushort4 u3 = *(const ushort4*)(hb + s3 * 64);
        dn += (w0 + w1) + (w2 + w3);
        acc[0] = fmaf(w0, bf2f(u0.x), fmaf(w1, bf2f(u1.x), fmaf(w2, bf2f(u2.x), fmaf(w3, bf2f(u3.x), acc[0]))));
        acc[1] = fmaf(w0, bf2f(u0.y), fmaf(w1, bf2f(u1.y), fmaf(w2, bf2f(u2.y), fmaf(w3, bf2f(u3.y), acc[1]))));
        acc[2] = fmaf(w0, bf2f(u0.z), fmaf(w1, bf2f(u1.z), fmaf(w2, bf2f(u2.z), fmaf(w3, bf2f(u3.z), acc[2]))));
        acc[3] = fmaf(w0, bf2f(u0.w), fmaf(w1, bf2f(u1.w), fmaf(w2, bf2f(u2.w), fmaf(w3, bf2f(u3.w), acc[3]))));
    }
    for (; e < e1; ++e) {
        int s0 = esrc[e];
        float w0 = __expf(lrelu(as2[s0] + adv));
        ushort4 u0 = *(const ushort4*)(hb + s0 * 64);
        dn += w0;
        acc[0] = fmaf(w0, bf2f(u0.x), acc[0]);
        acc[1] = fmaf(w0, bf2f(u0.y), acc[1]);
        acc[2] = fmaf(w0, bf2f(u0.z), acc[2]);
        acc[3] = fmaf(w0, bf2f(u0.w), acc[3]);
    }
    const float inv = 1.f / (dn + 1e-16f);
#pragma unroll
    for (int i = 0; i < 4; ++i) {
        int col = i * 16 + j2;                      // C2(j2*4+i)
        out[d * 64 + col] = acc[i] * inv + b2[col];
    }
}

// ---------------------------------------------------------------------------
// Workspace layout (bytes), total ~36.3 MB (r14 layout, unchanged):
//   counts @ 0            200,000  [zeroed; consumed as cursor by scatter]
//   off    @ 200,000      200,004
//   bsum   @ 400,032      800
//   as1    @ 400,896      800,000
//   ad1    @ 1,200,896    800,000
//   as2    @ 2,000,896    200,000
//   ad2    @ 2,200,896    200,000
//   esrc   @ 2,400,896    1,700,000  uint16
//   Wf1    @ 4,100,896    131,072
//   Wf2    @ 4,231,968    32,768
//   h1b    @ 4,264,736    25,600,000 bf16 C1-perm
//   h2b    @ 29,864,736   6,400,000  bf16 C2-perm
// ---------------------------------------------------------------------------
extern "C" void kernel_launch(void* const* d_in, const int* in_sizes, int n_in,
                              void* d_out, int out_size, void* d_ws, size_t ws_size,
                              hipStream_t stream)
{
    const float* x        = (const float*)d_in[0];
    const int*   ei       = (const int*)d_in[1];
    const float* W1       = (const float*)d_in[2];
    const float* att_src1 = (const float*)d_in[3];
    const float* att_dst1 = (const float*)d_in[4];
    const float* b1       = (const float*)d_in[5];
    const float* W2       = (const float*)d_in[6];
    const float* att_src2 = (const float*)d_in[7];
    const float* att_dst2 = (const float*)d_in[8];
    const float* b2       = (const float*)d_in[9];
    const int* src = ei;
    const int* dst = ei + E_RAW;
    float* out = (float*)d_out;

    char* ws = (char*)d_ws;
    int*            counts = (int*)(ws + 0);
    int*            off    = (int*)(ws + 200000);
    int*            bsum   = (int*)(ws + 400032);
    float*          as1    = (float*)(ws + 400896);
    float*          ad1    = (float*)(ws + 1200896);
    float*          as2    = (float*)(ws + 2000896);
    float*          ad2    = (float*)(ws + 2200896);
    unsigned short* esrc   = (unsigned short*)(ws + 2400896);
    unsigned short* Wf1    = (unsigned short*)(ws + 4100896);
    unsigned short* Wf2    = (unsigned short*)(ws + 4231968);
    unsigned short* h1b    = (unsigned short*)(ws + 4264736);
    unsigned short* h2b    = (unsigned short*)(ws + 29864736);

    hipMemsetAsync(counts, 0, 200000, stream);

    const int EB = (E_TOT + 255) / 256;
    k_prep_hist<<<EB, 256, 0, stream>>>(dst, counts, W1, W2, Wf1, Wf2);
    k_scan1  <<<NBC, 256, 0, stream>>>(counts, off, bsum);
    k_scan23 <<<NBC, 256, 0, stream>>>(off, bsum);
    k_gemm1_scatter<<<G1_BLKS + SCAT_BLKS, 256, 0, stream>>>(
        x, Wf1, att_src1, att_dst1, h1b, as1, ad1,
        src, dst, off, counts, esrc);
    k_gat1g2 <<<3125, 256, 0, stream>>>(esrc, off, as1, ad1, h1b, b1, Wf2,
                                        att_src2, att_dst2, h2b, as2, ad2);
    k_gather2<<<3125, 256, 0, stream>>>(esrc, off, as2, ad2, h2b, b2, out);
}